// Round 3
// baseline (499.670 us; speedup 1.0000x reference)
//
#include <hip/hip_runtime.h>
#include <hip/hip_bf16.h>

#define S 1024
#define D 64
#define BH 64
#define SCALE 0.125f

typedef __attribute__((ext_vector_type(8))) short short8;
typedef __attribute__((ext_vector_type(16))) float f32x16;

// packed bf16x2 via hardware cvt (RNE)
static __device__ __forceinline__ unsigned cvt_pk_bf16(float lo, float hi) {
  unsigned r;
  asm("v_cvt_pk_bf16_f32 %0, %1, %2" : "=v"(r) : "v"(lo), "v"(hi));
  return r;
}

static __device__ __forceinline__ short8 pack8(const float* f) {
  union { unsigned u[4]; short8 s; } r;
  r.u[0] = cvt_pk_bf16(f[0], f[1]);
  r.u[1] = cvt_pk_bf16(f[2], f[3]);
  r.u[2] = cvt_pk_bf16(f[4], f[5]);
  r.u[3] = cvt_pk_bf16(f[6], f[7]);
  return r.s;
}

static __device__ __forceinline__ short8 load_frag8(const float* p) {
  float4 a = *(const float4*)p;
  float4 b = *(const float4*)(p + 4);
  float f[8] = {a.x, a.y, a.z, a.w, b.x, b.y, b.z, b.w};
  return pack8(f);
}

// Phase 1: rcp[bh,kcol] = 1/sum_q exp(masked score). Round-1 structure
// (scalar mask loads, direct cndmask) + ballot bit-pack into
// packed[(bh*32 + ktile)*1024 + qrow] (block-contiguous 4KB region).
template <bool PACK>
__global__ __launch_bounds__(256) void colsum_kernel(
    const float* __restrict__ q, const float* __restrict__ k,
    const int* __restrict__ mask, float* __restrict__ rcp,
    unsigned* __restrict__ packed) {
  int tid = threadIdx.x;
  int wave = tid >> 6, lane = tid & 63;
  int l31 = lane & 31, hi = lane >> 5;
  int f = blockIdx.x;
  int fp = (f & 7) * 256 + (f >> 3);   // XCD-chunked, bijective (2048 = 8*256)
  int bh = fp >> 5, kbi = fp & 31;
  int kb = kbi * 32;
  const float* qh = q + (size_t)bh * S * D;
  const float* kh = k + (size_t)bh * S * D;
  const int* mh = mask + (size_t)bh * S * S;
  unsigned* pk = PACK ? packed + ((size_t)bh * 32 + kbi) * S : nullptr;

  short8 bfrag[4];
  const float* kp = kh + (size_t)(kb + l31) * D + hi * 8;
#pragma unroll
  for (int s = 0; s < 4; ++s) bfrag[s] = load_frag8(kp + s * 16);

  int kcol = kb + l31;
  float colpart = 0.f;
  for (int it = 0; it < 8; ++it) {
    int q0 = it * 128 + wave * 32;
    const float* qp = qh + (size_t)(q0 + l31) * D + hi * 8;
    short8 afrag[4];
#pragma unroll
    for (int s = 0; s < 4; ++s) afrag[s] = load_frag8(qp + s * 16);
    f32x16 acc = {};
#pragma unroll
    for (int s = 0; s < 4; ++s)
      acc = __builtin_amdgcn_mfma_f32_32x32x16_bf16(afrag[s], bfrag[s], acc, 0, 0, 0);
#pragma unroll
    for (int r = 0; r < 16; ++r) {
      int crow0 = (r & 3) + 8 * (r >> 2);
      int qrow = q0 + crow0 + 4 * hi;
      int m = mh[(size_t)qrow * S + kcol];
      if (PACK) {
        unsigned long long b = __ballot(m != 0);
        if (lane == 0) pk[q0 + crow0] = (unsigned)b;            // row crow(r,0)
        else if (lane == 32) pk[q0 + crow0 + 4] = (unsigned)(b >> 32);  // crow(r,1)
      }
      colpart += m ? __expf(acc[r] * SCALE) : 0.0f;
    }
  }
  colpart += __shfl_xor(colpart, 32, 64);
  __shared__ float red[4][32];
  if (lane < 32) red[wave][lane] = colpart;
  __syncthreads();
  if (tid < 32) {
    float t = red[0][tid] + red[1][tid] + red[2][tid] + red[3][tid];
    rcp[(size_t)bh * S + kb + tid] = 1.0f / t;
  }
}

// Phase 2: 2048 blocks x 4 waves. Block owns 32 q-rows; each wave does 8 of
// the 32 k-tiles (attn writes disjoint), out partials LDS-reduced at end.
template <bool PACKED>
__global__ __launch_bounds__(256, 6) void attn_out_kernel(
    const float* __restrict__ q, const float* __restrict__ k,
    const float* __restrict__ v, const int* __restrict__ mask,
    const unsigned* __restrict__ packed, const float* __restrict__ rcp,
    float* __restrict__ outp, float* __restrict__ attnp) {
  int tid = threadIdx.x;
  int wave = tid >> 6, lane = tid & 63;
  int l31 = lane & 31, hi = lane >> 5;
  int f = blockIdx.x;
  int fp = (f & 7) * 256 + (f >> 3);
  int bh = fp >> 5, qi = fp & 31;
  int qb = qi * 32;
  const float* qh = q + (size_t)bh * S * D;
  const float* kh = k + (size_t)bh * S * D;
  const float* vh = v + (size_t)bh * S * D;
  const int* mh = mask + (size_t)bh * S * S;
  const float* rch = rcp + (size_t)bh * S;
  float* ah = attnp + (size_t)bh * S * S;

  __shared__ float sm[4][32][33];     // per-wave P tile, pad 33 (conflict-free)
  __shared__ unsigned wlds[32][32];   // [ktile][qrow-local] packed mask words

  if (PACKED) {
    const unsigned* pkh = packed + (size_t)bh * 32 * S;
#pragma unroll
    for (int j = 0; j < 4; ++j) {
      int kt = j * 8 + (tid >> 5), row = tid & 31;
      wlds[kt][row] = pkh[(size_t)kt * S + qb + row];
    }
    __syncthreads();
  }

  short8 afrag[4];
  const float* qp = qh + (size_t)(qb + l31) * D + hi * 8;
#pragma unroll
  for (int s = 0; s < 4; ++s) afrag[s] = load_frag8(qp + s * 16);

  f32x16 oacc0 = {}, oacc1 = {};

  for (int t = 0; t < 8; ++t) {
    int kt = wave * 8 + t;
    int kb2 = kt * 32;
    const float* kp = kh + (size_t)(kb2 + l31) * D + hi * 8;
    short8 bfrag[4];
#pragma unroll
    for (int s = 0; s < 4; ++s) bfrag[s] = load_frag8(kp + s * 16);
    f32x16 acc = {};
#pragma unroll
    for (int s = 0; s < 4; ++s)
      acc = __builtin_amdgcn_mfma_f32_32x32x16_bf16(afrag[s], bfrag[s], acc, 0, 0, 0);

    int kcol = kb2 + l31;
    float rc = rch[kcol];
#pragma unroll
    for (int r = 0; r < 16; ++r) {
      int ql = (r & 3) + 8 * (r >> 2) + 4 * hi;
      int qrow = qb + ql;
      unsigned bit;
      if (PACKED) {
        bit = (wlds[kt][ql] >> l31) & 1u;   // broadcast per half-wave
      } else {
        bit = mh[(size_t)qrow * S + kcol] ? 1u : 0u;
      }
      float e = bit ? __expf(acc[r] * SCALE) * rc : 0.0f;
      __builtin_nontemporal_store(e, &ah[(size_t)qrow * S + kcol]);
      sm[wave][ql][l31] = e;
    }

    // PV: out[q][d] += P[q][kk] * v[kk][d]
#pragma unroll
    for (int s2 = 0; s2 < 2; ++s2) {
      float pv[8];
      const float* smrow = &sm[wave][l31][0];
#pragma unroll
      for (int e = 0; e < 8; ++e) pv[e] = smrow[s2 * 16 + hi * 8 + e];
      short8 pa = pack8(pv);
      const float* vp = vh + (size_t)(kb2 + s2 * 16 + hi * 8) * D + l31;
      float v0[8], v1[8];
#pragma unroll
      for (int e = 0; e < 8; ++e) {
        v0[e] = vp[(size_t)e * D];
        v1[e] = vp[(size_t)e * D + 32];
      }
      short8 vf0 = pack8(v0), vf1 = pack8(v1);
      oacc0 = __builtin_amdgcn_mfma_f32_32x32x16_bf16(pa, vf0, oacc0, 0, 0, 0);
      oacc1 = __builtin_amdgcn_mfma_f32_32x32x16_bf16(pa, vf1, oacc1, 0, 0, 0);
    }
  }

  // 4-way out reduction through sm (4224 floats; need 2*64*33 = 4224).
  __syncthreads();
  float* buf = &sm[0][0][0];
  if (wave >= 2) {
    float* dst = buf + (size_t)(wave - 2) * 2112 + lane * 33;
#pragma unroll
    for (int r = 0; r < 16; ++r) { dst[r] = oacc0[r]; dst[16 + r] = oacc1[r]; }
  }
  __syncthreads();
  if (wave < 2) {
    const float* src = buf + (size_t)wave * 2112 + lane * 33;
#pragma unroll
    for (int r = 0; r < 16; ++r) { oacc0[r] += src[r]; oacc1[r] += src[16 + r]; }
  }
  __syncthreads();
  if (wave == 1) {
    float* dst = buf + lane * 33;
#pragma unroll
    for (int r = 0; r < 16; ++r) { dst[r] = oacc0[r]; dst[16 + r] = oacc1[r]; }
  }
  __syncthreads();
  if (wave == 0) {
    const float* src = buf + lane * 33;
#pragma unroll
    for (int r = 0; r < 16; ++r) { oacc0[r] += src[r]; oacc1[r] += src[16 + r]; }
    float* oh = outp + (size_t)bh * S * D;
#pragma unroll
    for (int r = 0; r < 16; ++r) {
      int ql = (r & 3) + 8 * (r >> 2) + 4 * hi;
      oh[(size_t)(qb + ql) * D + l31] = oacc0[r];
      oh[(size_t)(qb + ql) * D + 32 + l31] = oacc1[r];
    }
  }
}

extern "C" void kernel_launch(void* const* d_in, const int* in_sizes, int n_in,
                              void* d_out, int out_size, void* d_ws, size_t ws_size,
                              hipStream_t stream) {
  const float* q = (const float*)d_in[0];
  const float* k = (const float*)d_in[1];
  const float* v = (const float*)d_in[2];
  const int* mask = (const int*)d_in[3];
  float* outp = (float*)d_out;
  float* attnp = outp + (size_t)BH * S * D;   // out first, then attn
  float* rcp = (float*)d_ws;                  // BH*S floats = 256 KB
  size_t rcp_bytes = (size_t)BH * S * 4;
  size_t packed_bytes = (size_t)BH * 32 * S * 4;  // 8.4 MB

  if (ws_size >= rcp_bytes + packed_bytes) {
    unsigned* packed = (unsigned*)((char*)d_ws + rcp_bytes);
    colsum_kernel<true><<<2048, 256, 0, stream>>>(q, k, mask, rcp, packed);
    attn_out_kernel<true><<<2048, 256, 0, stream>>>(q, k, v, mask, packed, rcp,
                                                    outp, attnp);
  } else {
    colsum_kernel<false><<<2048, 256, 0, stream>>>(q, k, mask, rcp, nullptr);
    attn_out_kernel<false><<<2048, 256, 0, stream>>>(q, k, v, mask, nullptr, rcp,
                                                     outp, attnp);
  }
}

// Round 4
// 445.941 us; speedup vs baseline: 1.1205x; 1.1205x over previous
//
#include <hip/hip_runtime.h>
#include <hip/hip_bf16.h>

#define S 1024
#define D 64
#define BH 64
#define SCALE 0.125f

typedef __attribute__((ext_vector_type(8))) short short8;
typedef __attribute__((ext_vector_type(16))) float f32x16;

// packed bf16x2 via hardware cvt (RNE)
static __device__ __forceinline__ unsigned cvt_pk_bf16(float lo, float hi) {
  unsigned r;
  asm("v_cvt_pk_bf16_f32 %0, %1, %2" : "=v"(r) : "v"(lo), "v"(hi));
  return r;
}

static __device__ __forceinline__ short8 pack8(const float* f) {
  union { unsigned u[4]; short8 s; } r;
  r.u[0] = cvt_pk_bf16(f[0], f[1]);
  r.u[1] = cvt_pk_bf16(f[2], f[3]);
  r.u[2] = cvt_pk_bf16(f[4], f[5]);
  r.u[3] = cvt_pk_bf16(f[6], f[7]);
  return r.s;
}

static __device__ __forceinline__ short8 load_frag8(const float* p) {
  float4 a = *(const float4*)p;
  float4 b = *(const float4*)(p + 4);
  float f[8] = {a.x, a.y, a.z, a.w, b.x, b.y, b.z, b.w};
  return pack8(f);
}

// Phase 1 (round-1 structure): rcp[bh,kcol] = 1/sum_q exp(masked score).
// Adds register-assembled mask bit-pack: packed[bh][qrow>>5][kcol],
// bit (qrow&31). 8 coalesced 128B stores per block, zero divergence.
template <bool PACK>
__global__ __launch_bounds__(256) void colsum_kernel(
    const float* __restrict__ q, const float* __restrict__ k,
    const int* __restrict__ mask, float* __restrict__ rcp,
    unsigned* __restrict__ packed) {
  int tid = threadIdx.x;
  int wave = tid >> 6, lane = tid & 63;
  int l31 = lane & 31, hi = lane >> 5;
  int kb = blockIdx.x * 32;
  int bh = blockIdx.y;
  const float* qh = q + (size_t)bh * S * D;
  const float* kh = k + (size_t)bh * S * D;
  const int* mh = mask + (size_t)bh * S * S;

  short8 bfrag[4];
  const float* kp = kh + (size_t)(kb + l31) * D + hi * 8;
#pragma unroll
  for (int s = 0; s < 4; ++s) bfrag[s] = load_frag8(kp + s * 16);

  int kcol = kb + l31;
  float colpart = 0.f;
  for (int it = 0; it < 8; ++it) {
    int q0 = it * 128 + wave * 32;   // == (it*4+wave)*32, one 32-row q-word
    const float* qp = qh + (size_t)(q0 + l31) * D + hi * 8;
    short8 afrag[4];
#pragma unroll
    for (int s = 0; s < 4; ++s) afrag[s] = load_frag8(qp + s * 16);
    f32x16 acc = {};
#pragma unroll
    for (int s = 0; s < 4; ++s)
      acc = __builtin_amdgcn_mfma_f32_32x32x16_bf16(afrag[s], bfrag[s], acc, 0, 0, 0);

    unsigned w = 0;
#pragma unroll
    for (int r = 0; r < 16; ++r) {
      int crow0 = (r & 3) + 8 * (r >> 2);
      int qrow = q0 + crow0 + 4 * hi;
      int m = mh[(size_t)qrow * S + kcol];
      if (PACK) w |= (m ? 1u : 0u) << (crow0 + 4 * hi);
      colpart += m ? __expf(acc[r] * SCALE) : 0.0f;
    }
    if (PACK) {
      w |= __shfl_xor(w, 32, 64);    // merge the two 16-bit halves
      if (lane < 32) {
        int qw = it * 4 + wave;
        packed[((size_t)bh * 32 + qw) * S + kb + l31] = w;  // 128B coalesced
      }
    }
  }
  colpart += __shfl_xor(colpart, 32, 64);
  __shared__ float red[4][32];
  if (lane < 32) red[wave][lane] = colpart;
  __syncthreads();
  if (tid < 32) {
    float t = red[0][tid] + red[1][tid] + red[2][tid] + red[3][tid];
    rcp[(size_t)bh * S + kb + tid] = 1.0f / t;
  }
}

// Phase 2 (round-1 structure exactly): 512 blocks x 4 waves, wave owns 32
// q-rows, full k-sweep per wave. Only change: mask comes from the packed
// bits staged in 16KB LDS (1 loop-invariant ds_read per tile) instead of
// 16 global dword loads per tile.
template <bool PACKED>
__global__ __launch_bounds__(256) void attn_out_kernel(
    const float* __restrict__ q, const float* __restrict__ k,
    const float* __restrict__ v, const int* __restrict__ mask,
    const unsigned* __restrict__ packed, const float* __restrict__ rcp,
    float* __restrict__ outp, float* __restrict__ attnp) {
  int tid = threadIdx.x;
  int wave = tid >> 6, lane = tid & 63;
  int l31 = lane & 31, hi = lane >> 5;
  int bh = blockIdx.y;
  int qb = blockIdx.x * 128 + wave * 32;
  const float* qh = q + (size_t)bh * S * D;
  const float* kh = k + (size_t)bh * S * D;
  const float* vh = v + (size_t)bh * S * D;
  const int* mh = mask + (size_t)bh * S * S;
  const float* rch = rcp + (size_t)bh * S;
  float* ah = attnp + (size_t)bh * S * S;

  __shared__ float sm[4][32][33];    // per-wave P tile, +1 pad
  __shared__ unsigned wlds[4][1024]; // [wave's q-word][kcol] packed mask

  if (PACKED) {
    const int4* src = (const int4*)(packed + ((size_t)bh * 32 + blockIdx.x * 4) * S);
    int4* dst = (int4*)&wlds[0][0];
#pragma unroll
    for (int j = 0; j < 4; ++j) dst[tid + j * 256] = src[tid + j * 256];
    __syncthreads();
  }

  short8 afrag[4];
  const float* qp = qh + (size_t)(qb + l31) * D + hi * 8;
#pragma unroll
  for (int s = 0; s < 4; ++s) afrag[s] = load_frag8(qp + s * 16);

  f32x16 oacc0 = {}, oacc1 = {};

  for (int kt = 0; kt < 32; ++kt) {
    int kb2 = kt * 32;
    const float* kp = kh + (size_t)(kb2 + l31) * D + hi * 8;
    short8 bfrag[4];
#pragma unroll
    for (int s = 0; s < 4; ++s) bfrag[s] = load_frag8(kp + s * 16);
    f32x16 acc = {};
#pragma unroll
    for (int s = 0; s < 4; ++s)
      acc = __builtin_amdgcn_mfma_f32_32x32x16_bf16(afrag[s], bfrag[s], acc, 0, 0, 0);

    int kcol = kb2 + l31;
    float rc = rch[kcol];
    unsigned mw = PACKED ? wlds[wave][kcol] : 0u;  // 1 ds_read, banks 0..31
#pragma unroll
    for (int r = 0; r < 16; ++r) {
      int ql = (r & 3) + 8 * (r >> 2) + 4 * hi;
      int qrow = qb + ql;
      unsigned bit;
      if (PACKED) bit = (mw >> ql) & 1u;
      else        bit = mh[(size_t)qrow * S + kcol] ? 1u : 0u;
      float e = bit ? __expf(acc[r] * SCALE) * rc : 0.0f;
      ah[(size_t)qrow * S + kcol] = e;   // plain coalesced store
      sm[wave][ql][l31] = e;
    }

    // PV: out[q][d] += P[q][kk] * v[kk][d]
#pragma unroll
    for (int s2 = 0; s2 < 2; ++s2) {
      float pv[8];
      const float* smrow = &sm[wave][l31][0];
#pragma unroll
      for (int e = 0; e < 8; ++e) pv[e] = smrow[s2 * 16 + hi * 8 + e];
      short8 pa = pack8(pv);
      const float* vp = vh + (size_t)(kb2 + s2 * 16 + hi * 8) * D + l31;
      float v0[8], v1[8];
#pragma unroll
      for (int e = 0; e < 8; ++e) {
        v0[e] = vp[(size_t)e * D];
        v1[e] = vp[(size_t)e * D + 32];
      }
      short8 vf0 = pack8(v0), vf1 = pack8(v1);
      oacc0 = __builtin_amdgcn_mfma_f32_32x32x16_bf16(pa, vf0, oacc0, 0, 0, 0);
      oacc1 = __builtin_amdgcn_mfma_f32_32x32x16_bf16(pa, vf1, oacc1, 0, 0, 0);
    }
  }

  float* oh = outp + (size_t)bh * S * D;
#pragma unroll
  for (int r = 0; r < 16; ++r) {
    int ql = (r & 3) + 8 * (r >> 2) + 4 * hi;
    oh[(size_t)(qb + ql) * D + l31] = oacc0[r];
    oh[(size_t)(qb + ql) * D + 32 + l31] = oacc1[r];
  }
}

extern "C" void kernel_launch(void* const* d_in, const int* in_sizes, int n_in,
                              void* d_out, int out_size, void* d_ws, size_t ws_size,
                              hipStream_t stream) {
  const float* q = (const float*)d_in[0];
  const float* k = (const float*)d_in[1];
  const float* v = (const float*)d_in[2];
  const int* mask = (const int*)d_in[3];
  float* outp = (float*)d_out;
  float* attnp = outp + (size_t)BH * S * D;   // out first, then attn
  float* rcp = (float*)d_ws;                  // BH*S floats = 256 KB
  size_t rcp_bytes = (size_t)BH * S * 4;
  size_t packed_bytes = (size_t)BH * 32 * S * 4;  // 8.4 MB

  if (ws_size >= rcp_bytes + packed_bytes) {
    unsigned* packed = (unsigned*)((char*)d_ws + rcp_bytes);
    colsum_kernel<true><<<dim3(S / 32, BH), 256, 0, stream>>>(q, k, mask, rcp, packed);
    attn_out_kernel<true><<<dim3(S / 128, BH), 256, 0, stream>>>(q, k, v, mask, packed,
                                                                 rcp, outp, attnp);
  } else {
    colsum_kernel<false><<<dim3(S / 32, BH), 256, 0, stream>>>(q, k, mask, rcp, nullptr);
    attn_out_kernel<false><<<dim3(S / 128, BH), 256, 0, stream>>>(q, k, v, mask, nullptr,
                                                                  rcp, outp, attnp);
  }
}

// Round 5
// 266.246 us; speedup vs baseline: 1.8767x; 1.6749x over previous
//
#include <hip/hip_runtime.h>
#include <hip/hip_bf16.h>

#define S 1024
#define D 64
#define BH 64
#define SCALE 0.125f

typedef __attribute__((ext_vector_type(8))) short short8;
typedef __attribute__((ext_vector_type(16))) float f32x16;

// fp32 -> bf16 RNE. Plain bit ops, NO inline asm: asm cvt_pk measured 2x
// slower here (rounds 2-4: VALUBusy 24%->8%) — matches learn_hip m240.
static __device__ __forceinline__ unsigned short f2bf(float f) {
  union { float f; unsigned u; } v; v.f = f;
  return (unsigned short)((v.u + 0x7fffu + ((v.u >> 16) & 1u)) >> 16);
}

static __device__ __forceinline__ short8 load_frag8_f32(const float* p) {
  float4 a = *(const float4*)p;
  float4 b = *(const float4*)(p + 4);
  short8 r;
  r[0] = f2bf(a.x); r[1] = f2bf(a.y); r[2] = f2bf(a.z); r[3] = f2bf(a.w);
  r[4] = f2bf(b.x); r[5] = f2bf(b.y); r[6] = f2bf(b.z); r[7] = f2bf(b.w);
  return r;
}

// Pre-pass: q,k,v fp32 -> bf16 (row-major unchanged). Grid (1024,3) x 256,
// each thread converts 2 chunks of 8 floats. ~75 MB traffic, BW-bound.
__global__ __launch_bounds__(256) void cvt_kernel(
    const float* __restrict__ s0, const float* __restrict__ s1,
    const float* __restrict__ s2, unsigned short* __restrict__ d0,
    unsigned short* __restrict__ d1, unsigned short* __restrict__ d2) {
  const float* s = blockIdx.y == 0 ? s0 : (blockIdx.y == 1 ? s1 : s2);
  unsigned short* d = blockIdx.y == 0 ? d0 : (blockIdx.y == 1 ? d1 : d2);
  size_t i = (size_t)(blockIdx.x * 256 + threadIdx.x) * 8;
#pragma unroll
  for (int c = 0; c < 2; ++c, i += (size_t)1024 * 256 * 8)
    *(short8*)(d + i) = load_frag8_f32(s + i);
}

// Phase 1: rcp[bh,kcol] = 1/sum_q exp(masked score) + mask bit-pack
// packed[bh][qrow>>5][kcol] bit (qrow&31). Round-1 structure.
template <bool PRE, bool PACK>
__global__ __launch_bounds__(256) void colsum_kernel(
    const float* __restrict__ q, const float* __restrict__ k,
    const unsigned short* __restrict__ qbf, const unsigned short* __restrict__ kbf,
    const int* __restrict__ mask, float* __restrict__ rcp,
    unsigned* __restrict__ packed) {
  int tid = threadIdx.x;
  int wave = tid >> 6, lane = tid & 63;
  int l31 = lane & 31, hi = lane >> 5;
  int kb = blockIdx.x * 32;
  int bh = blockIdx.y;
  const int* mh = mask + (size_t)bh * S * S;

  short8 bfrag[4];
  if (PRE) {
    const unsigned short* kp = kbf + ((size_t)bh * S + kb + l31) * D + hi * 8;
#pragma unroll
    for (int s = 0; s < 4; ++s) bfrag[s] = *(const short8*)(kp + s * 16);
  } else {
    const float* kp = k + ((size_t)bh * S + kb + l31) * D + hi * 8;
#pragma unroll
    for (int s = 0; s < 4; ++s) bfrag[s] = load_frag8_f32(kp + s * 16);
  }

  int kcol = kb + l31;
  float colpart = 0.f;
  for (int it = 0; it < 8; ++it) {
    int q0 = it * 128 + wave * 32;  // one 32-row q-word: index it*4+wave
    short8 afrag[4];
    if (PRE) {
      const unsigned short* qp = qbf + ((size_t)bh * S + q0 + l31) * D + hi * 8;
#pragma unroll
      for (int s = 0; s < 4; ++s) afrag[s] = *(const short8*)(qp + s * 16);
    } else {
      const float* qp = q + ((size_t)bh * S + q0 + l31) * D + hi * 8;
#pragma unroll
      for (int s = 0; s < 4; ++s) afrag[s] = load_frag8_f32(qp + s * 16);
    }
    f32x16 acc = {};
#pragma unroll
    for (int s = 0; s < 4; ++s)
      acc = __builtin_amdgcn_mfma_f32_32x32x16_bf16(afrag[s], bfrag[s], acc, 0, 0, 0);

    unsigned w = 0;
#pragma unroll
    for (int r = 0; r < 16; ++r) {
      int crow0 = (r & 3) + 8 * (r >> 2);
      int qrow = q0 + crow0 + 4 * hi;
      int m = mh[(size_t)qrow * S + kcol];
      if (PACK) w |= (m ? 1u : 0u) << (crow0 + 4 * hi);
      colpart += m ? __expf(acc[r] * SCALE) : 0.0f;
    }
    if (PACK) {
      w |= __shfl_xor(w, 32, 64);
      if (lane < 32) {
        int qw = it * 4 + wave;
        packed[((size_t)bh * 32 + qw) * S + kb + l31] = w;  // 128B coalesced
      }
    }
  }
  colpart += __shfl_xor(colpart, 32, 64);
  __shared__ float red[4][32];
  if (lane < 32) red[wave][lane] = colpart;
  __syncthreads();
  if (tid < 32) {
    float t = red[0][tid] + red[1][tid] + red[2][tid] + red[3][tid];
    rcp[(size_t)bh * S + kb + tid] = 1.0f / t;
  }
}

// Phase 2 (round-1 structure): 512 blocks x 4 waves, wave owns 32 q-rows,
// full k-sweep. Mask from packed bits in LDS; q/k/v direct bf16 loads.
template <bool PRE, bool PACKED>
__global__ __launch_bounds__(256) void attn_out_kernel(
    const float* __restrict__ q, const float* __restrict__ k,
    const float* __restrict__ v, const unsigned short* __restrict__ qbf,
    const unsigned short* __restrict__ kbf, const unsigned short* __restrict__ vbf,
    const int* __restrict__ mask, const unsigned* __restrict__ packed,
    const float* __restrict__ rcp, float* __restrict__ outp,
    float* __restrict__ attnp) {
  int tid = threadIdx.x;
  int wave = tid >> 6, lane = tid & 63;
  int l31 = lane & 31, hi = lane >> 5;
  int bh = blockIdx.y;
  int qb = blockIdx.x * 128 + wave * 32;
  const int* mh = mask + (size_t)bh * S * S;
  const float* rch = rcp + (size_t)bh * S;
  float* ah = attnp + (size_t)bh * S * S;

  __shared__ float sm[4][32][33];    // per-wave P tile, +1 pad
  __shared__ unsigned wlds[4][1024]; // [q-word][kcol] packed mask

  if (PACKED) {
    const int4* src = (const int4*)(packed + ((size_t)bh * 32 + blockIdx.x * 4) * S);
    int4* dst = (int4*)&wlds[0][0];
#pragma unroll
    for (int j = 0; j < 4; ++j) dst[tid + j * 256] = src[tid + j * 256];
    __syncthreads();
  }

  short8 afrag[4];
  if (PRE) {
    const unsigned short* qp = qbf + ((size_t)bh * S + qb + l31) * D + hi * 8;
#pragma unroll
    for (int s = 0; s < 4; ++s) afrag[s] = *(const short8*)(qp + s * 16);
  } else {
    const float* qp = q + ((size_t)bh * S + qb + l31) * D + hi * 8;
#pragma unroll
    for (int s = 0; s < 4; ++s) afrag[s] = load_frag8_f32(qp + s * 16);
  }

  f32x16 oacc0 = {}, oacc1 = {};

  for (int kt = 0; kt < 32; ++kt) {
    int kb2 = kt * 32;
    short8 bfrag[4];
    if (PRE) {
      const unsigned short* kp = kbf + ((size_t)bh * S + kb2 + l31) * D + hi * 8;
#pragma unroll
      for (int s = 0; s < 4; ++s) bfrag[s] = *(const short8*)(kp + s * 16);
    } else {
      const float* kp = k + ((size_t)bh * S + kb2 + l31) * D + hi * 8;
#pragma unroll
      for (int s = 0; s < 4; ++s) bfrag[s] = load_frag8_f32(kp + s * 16);
    }
    f32x16 acc = {};
#pragma unroll
    for (int s = 0; s < 4; ++s)
      acc = __builtin_amdgcn_mfma_f32_32x32x16_bf16(afrag[s], bfrag[s], acc, 0, 0, 0);

    int kcol = kb2 + l31;
    float rc = rch[kcol];
    unsigned mw = PACKED ? wlds[wave][kcol] : 0u;
#pragma unroll
    for (int r = 0; r < 16; ++r) {
      int ql = (r & 3) + 8 * (r >> 2) + 4 * hi;
      int qrow = qb + ql;
      unsigned bit;
      if (PACKED) bit = (mw >> ql) & 1u;
      else        bit = mh[(size_t)qrow * S + kcol] ? 1u : 0u;
      float e = bit ? __expf(acc[r] * SCALE) * rc : 0.0f;
      ah[(size_t)qrow * S + kcol] = e;
      sm[wave][ql][l31] = e;
    }

    // PV: out[q][d] += P[q][kk] * v[kk][d]
#pragma unroll
    for (int s2 = 0; s2 < 2; ++s2) {
      short8 pa;
      const float* smrow = &sm[wave][l31][0];
#pragma unroll
      for (int e = 0; e < 8; ++e) pa[e] = f2bf(smrow[s2 * 16 + hi * 8 + e]);
      short8 vf0, vf1;
      if (PRE) {
        const unsigned short* vp =
            vbf + ((size_t)bh * S + kb2 + s2 * 16 + hi * 8) * D + l31;
#pragma unroll
        for (int e = 0; e < 8; ++e) {
          vf0[e] = (short)vp[(size_t)e * D];
          vf1[e] = (short)vp[(size_t)e * D + 32];
        }
      } else {
        const float* vp = v + ((size_t)bh * S + kb2 + s2 * 16 + hi * 8) * D + l31;
#pragma unroll
        for (int e = 0; e < 8; ++e) {
          vf0[e] = f2bf(vp[(size_t)e * D]);
          vf1[e] = f2bf(vp[(size_t)e * D + 32]);
        }
      }
      oacc0 = __builtin_amdgcn_mfma_f32_32x32x16_bf16(pa, vf0, oacc0, 0, 0, 0);
      oacc1 = __builtin_amdgcn_mfma_f32_32x32x16_bf16(pa, vf1, oacc1, 0, 0, 0);
    }
  }

  float* oh = outp + (size_t)bh * S * D;
#pragma unroll
  for (int r = 0; r < 16; ++r) {
    int ql = (r & 3) + 8 * (r >> 2) + 4 * hi;
    oh[(size_t)(qb + ql) * D + l31] = oacc0[r];
    oh[(size_t)(qb + ql) * D + 32 + l31] = oacc1[r];
  }
}

extern "C" void kernel_launch(void* const* d_in, const int* in_sizes, int n_in,
                              void* d_out, int out_size, void* d_ws, size_t ws_size,
                              hipStream_t stream) {
  const float* q = (const float*)d_in[0];
  const float* k = (const float*)d_in[1];
  const float* v = (const float*)d_in[2];
  const int* mask = (const int*)d_in[3];
  float* outp = (float*)d_out;
  float* attnp = outp + (size_t)BH * S * D;  // out first, then attn
  float* rcp = (float*)d_ws;                 // 256 KB
  size_t rcp_bytes = (size_t)BH * S * 4;
  size_t packed_bytes = (size_t)BH * 32 * S * 4;        // 8.4 MB
  size_t bf_bytes = (size_t)BH * S * D * 2;             // 8.4 MB each

  unsigned* packed = (unsigned*)((char*)d_ws + rcp_bytes);
  unsigned short* qbf = (unsigned short*)((char*)d_ws + rcp_bytes + packed_bytes);
  unsigned short* kbf = qbf + (size_t)BH * S * D;
  unsigned short* vbf = kbf + (size_t)BH * S * D;

  if (ws_size >= rcp_bytes + packed_bytes + 3 * bf_bytes) {
    cvt_kernel<<<dim3(1024, 3), 256, 0, stream>>>(q, k, v, qbf, kbf, vbf);
    colsum_kernel<true, true><<<dim3(S / 32, BH), 256, 0, stream>>>(
        q, k, qbf, kbf, mask, rcp, packed);
    attn_out_kernel<true, true><<<dim3(S / 128, BH), 256, 0, stream>>>(
        q, k, v, qbf, kbf, vbf, mask, packed, rcp, outp, attnp);
  } else if (ws_size >= rcp_bytes + packed_bytes) {
    colsum_kernel<false, true><<<dim3(S / 32, BH), 256, 0, stream>>>(
        q, k, nullptr, nullptr, mask, rcp, packed);
    attn_out_kernel<false, true><<<dim3(S / 128, BH), 256, 0, stream>>>(
        q, k, v, nullptr, nullptr, nullptr, mask, packed, rcp, outp, attnp);
  } else {
    colsum_kernel<false, false><<<dim3(S / 32, BH), 256, 0, stream>>>(
        q, k, nullptr, nullptr, mask, rcp, nullptr);
    attn_out_kernel<false, false><<<dim3(S / 128, BH), 256, 0, stream>>>(
        q, k, v, nullptr, nullptr, nullptr, mask, nullptr, rcp, outp, attnp);
  }
}

// Round 6
// 250.923 us; speedup vs baseline: 1.9913x; 1.0611x over previous
//
#include <hip/hip_runtime.h>
#include <hip/hip_bf16.h>

#define S 1024
#define D 64
#define BH 64
#define SCALE 0.125f

typedef __attribute__((ext_vector_type(8))) short short8;
typedef __attribute__((ext_vector_type(16))) float f32x16;

// fp32 -> bf16 RNE. Plain bit ops, NO inline asm (asm cvt_pk measured ~2x
// slower in rounds 2-4; matches learn_hip m240).
static __device__ __forceinline__ unsigned short f2bf(float f) {
  union { float f; unsigned u; } v; v.f = f;
  return (unsigned short)((v.u + 0x7fffu + ((v.u >> 16) & 1u)) >> 16);
}

static __device__ __forceinline__ short8 load_frag8_f32(const float* p) {
  float4 a = *(const float4*)p;
  float4 b = *(const float4*)(p + 4);
  short8 r;
  r[0] = f2bf(a.x); r[1] = f2bf(a.y); r[2] = f2bf(a.z); r[3] = f2bf(a.w);
  r[4] = f2bf(b.x); r[5] = f2bf(b.y); r[6] = f2bf(b.z); r[7] = f2bf(b.w);
  return r;
}

// Pre-pass A: q,k fp32 -> bf16 straight convert.
__global__ __launch_bounds__(256) void cvt_kernel(
    const float* __restrict__ s0, const float* __restrict__ s1,
    unsigned short* __restrict__ d0, unsigned short* __restrict__ d1) {
  const float* s = blockIdx.y == 0 ? s0 : s1;
  unsigned short* d = blockIdx.y == 0 ? d0 : d1;
  size_t i = (size_t)(blockIdx.x * 256 + threadIdx.x) * 8;
#pragma unroll
  for (int c = 0; c < 2; ++c, i += (size_t)1024 * 256 * 8)
    *(short8*)(d + i) = load_frag8_f32(s + i);
}

// Pre-pass B: v fp32 [bh][s][d] -> vT bf16 [bh][d][s] via 64x64 LDS tile.
__global__ __launch_bounds__(256) void vt_kernel(
    const float* __restrict__ v, unsigned short* __restrict__ vt) {
  __shared__ float t[64][65];
  int bh = blockIdx.y;
  int s0 = blockIdx.x * 64;
  int tid = threadIdx.x;
  // coalesced read: thread covers row r, 16 floats
  {
    int r = tid >> 2, c4 = (tid & 3) * 16;
    const float4* src = (const float4*)(v + ((size_t)bh * S + s0 + r) * D + c4);
#pragma unroll
    for (int j = 0; j < 4; ++j) {
      float4 x = src[j];
      t[r][c4 + j * 4 + 0] = x.x; t[r][c4 + j * 4 + 1] = x.y;
      t[r][c4 + j * 4 + 2] = x.z; t[r][c4 + j * 4 + 3] = x.w;
    }
  }
  __syncthreads();
  // transposed write: lane-quad (4 thr, same d-row... thread d=tid>>2 covers
  // 16 s) -> 128B-coalesced lines per quad; LDS col-read 2-way alias = free
  {
    int d = tid >> 2, sc = (tid & 3) * 16;
    unsigned short* dst = vt + ((size_t)bh * D + d) * S + s0 + sc;
    short8 o0, o1;
#pragma unroll
    for (int j = 0; j < 8; ++j) {
      o0[j] = (short)f2bf(t[sc + j][d]);
      o1[j] = (short)f2bf(t[sc + 8 + j][d]);
    }
    *(short8*)dst = o0;
    *(short8*)(dst + 8) = o1;
  }
}

// Phase 1: rcp[bh,kcol] = 1/sum_q exp(masked score) + mask bit-pack
// packed[bh][qrow>>5][kcol] bit (qrow&31). Round-1 structure.
template <bool PRE, bool PACK>
__global__ __launch_bounds__(256) void colsum_kernel(
    const float* __restrict__ q, const float* __restrict__ k,
    const unsigned short* __restrict__ qbf, const unsigned short* __restrict__ kbf,
    const int* __restrict__ mask, float* __restrict__ rcp,
    unsigned* __restrict__ packed) {
  int tid = threadIdx.x;
  int wave = tid >> 6, lane = tid & 63;
  int l31 = lane & 31, hi = lane >> 5;
  int kb = blockIdx.x * 32;
  int bh = blockIdx.y;
  const int* mh = mask + (size_t)bh * S * S;

  short8 bfrag[4];
  if (PRE) {
    const unsigned short* kp = kbf + ((size_t)bh * S + kb + l31) * D + hi * 8;
#pragma unroll
    for (int s = 0; s < 4; ++s) bfrag[s] = *(const short8*)(kp + s * 16);
  } else {
    const float* kp = k + ((size_t)bh * S + kb + l31) * D + hi * 8;
#pragma unroll
    for (int s = 0; s < 4; ++s) bfrag[s] = load_frag8_f32(kp + s * 16);
  }

  int kcol = kb + l31;
  float colpart = 0.f;
  for (int it = 0; it < 8; ++it) {
    int q0 = it * 128 + wave * 32;  // one 32-row q-word: index it*4+wave
    short8 afrag[4];
    if (PRE) {
      const unsigned short* qp = qbf + ((size_t)bh * S + q0 + l31) * D + hi * 8;
#pragma unroll
      for (int s = 0; s < 4; ++s) afrag[s] = *(const short8*)(qp + s * 16);
    } else {
      const float* qp = q + ((size_t)bh * S + q0 + l31) * D + hi * 8;
#pragma unroll
      for (int s = 0; s < 4; ++s) afrag[s] = load_frag8_f32(qp + s * 16);
    }
    f32x16 acc = {};
#pragma unroll
    for (int s = 0; s < 4; ++s)
      acc = __builtin_amdgcn_mfma_f32_32x32x16_bf16(afrag[s], bfrag[s], acc, 0, 0, 0);

    unsigned w = 0;
#pragma unroll
    for (int r = 0; r < 16; ++r) {
      int crow0 = (r & 3) + 8 * (r >> 2);
      int qrow = q0 + crow0 + 4 * hi;
      int m = mh[(size_t)qrow * S + kcol];
      if (PACK) w |= (m ? 1u : 0u) << (crow0 + 4 * hi);
      colpart += m ? __expf(acc[r] * SCALE) : 0.0f;
    }
    if (PACK) {
      w |= __shfl_xor(w, 32, 64);
      if (lane < 32) {
        int qw = it * 4 + wave;
        packed[((size_t)bh * 32 + qw) * S + kb + l31] = w;  // 128B coalesced
      }
    }
  }
  colpart += __shfl_xor(colpart, 32, 64);
  __shared__ float red[4][32];
  if (lane < 32) red[wave][lane] = colpart;
  __syncthreads();
  if (tid < 32) {
    float t = red[0][tid] + red[1][tid] + red[2][tid] + red[3][tid];
    rcp[(size_t)bh * S + kb + tid] = 1.0f / t;
  }
}

// Phase 2 (round-1 structure): 512 blocks x 4 waves, wave owns 32 q-rows,
// full k-sweep. Mask from packed bits in LDS; q/k bf16 frag loads; V from
// transposed bf16 vT => one 16B load per PV B-fragment.
template <bool PRE, bool PACKED>
__global__ __launch_bounds__(256) void attn_out_kernel(
    const float* __restrict__ q, const float* __restrict__ k,
    const float* __restrict__ v, const unsigned short* __restrict__ qbf,
    const unsigned short* __restrict__ kbf, const unsigned short* __restrict__ vt,
    const int* __restrict__ mask, const unsigned* __restrict__ packed,
    const float* __restrict__ rcp, float* __restrict__ outp,
    float* __restrict__ attnp) {
  int tid = threadIdx.x;
  int wave = tid >> 6, lane = tid & 63;
  int l31 = lane & 31, hi = lane >> 5;
  int bh = blockIdx.y;
  int qb = blockIdx.x * 128 + wave * 32;
  const int* mh = mask + (size_t)bh * S * S;
  const float* rch = rcp + (size_t)bh * S;
  float* ah = attnp + (size_t)bh * S * S;
  const unsigned short* vtb = PRE ? vt + (size_t)bh * D * S : nullptr;

  __shared__ float sm[4][32][33];    // per-wave P tile, +1 pad
  __shared__ unsigned wlds[4][1024]; // [q-word][kcol] packed mask

  if (PACKED) {
    const int4* src = (const int4*)(packed + ((size_t)bh * 32 + blockIdx.x * 4) * S);
    int4* dst = (int4*)&wlds[0][0];
#pragma unroll
    for (int j = 0; j < 4; ++j) dst[tid + j * 256] = src[tid + j * 256];
    __syncthreads();
  }

  short8 afrag[4];
  if (PRE) {
    const unsigned short* qp = qbf + ((size_t)bh * S + qb + l31) * D + hi * 8;
#pragma unroll
    for (int s = 0; s < 4; ++s) afrag[s] = *(const short8*)(qp + s * 16);
  } else {
    const float* qp = q + ((size_t)bh * S + qb + l31) * D + hi * 8;
#pragma unroll
    for (int s = 0; s < 4; ++s) afrag[s] = load_frag8_f32(qp + s * 16);
  }

  f32x16 oacc0 = {}, oacc1 = {};

  for (int kt = 0; kt < 32; ++kt) {
    int kb2 = kt * 32;
    short8 bfrag[4];
    if (PRE) {
      const unsigned short* kp = kbf + ((size_t)bh * S + kb2 + l31) * D + hi * 8;
#pragma unroll
      for (int s = 0; s < 4; ++s) bfrag[s] = *(const short8*)(kp + s * 16);
    } else {
      const float* kp = k + ((size_t)bh * S + kb2 + l31) * D + hi * 8;
#pragma unroll
      for (int s = 0; s < 4; ++s) bfrag[s] = load_frag8_f32(kp + s * 16);
    }
    f32x16 acc = {};
#pragma unroll
    for (int s = 0; s < 4; ++s)
      acc = __builtin_amdgcn_mfma_f32_32x32x16_bf16(afrag[s], bfrag[s], acc, 0, 0, 0);

    int kcol = kb2 + l31;
    float rc = rch[kcol];
    unsigned mw = PACKED ? wlds[wave][kcol] : 0u;
#pragma unroll
    for (int r = 0; r < 16; ++r) {
      int ql = (r & 3) + 8 * (r >> 2) + 4 * hi;
      int qrow = qb + ql;
      unsigned bit;
      if (PACKED) bit = (mw >> ql) & 1u;
      else        bit = mh[(size_t)qrow * S + kcol] ? 1u : 0u;
      float e = bit ? __expf(acc[r] * SCALE) * rc : 0.0f;
      ah[(size_t)qrow * S + kcol] = e;
      sm[wave][ql][l31] = e;
    }

    // PV: out[q][d] += P[q][kk] * v[kk][d]
#pragma unroll
    for (int s2 = 0; s2 < 2; ++s2) {
      short8 pa;
      const float* smrow = &sm[wave][l31][0];
#pragma unroll
      for (int e = 0; e < 8; ++e) pa[e] = (short)f2bf(smrow[s2 * 16 + hi * 8 + e]);
      short8 vf0, vf1;
      if (PRE) {
        const unsigned short* vp0 = vtb + (size_t)l31 * S + kb2 + s2 * 16 + hi * 8;
        vf0 = *(const short8*)vp0;                     // V[kk][d=l31]
        vf1 = *(const short8*)(vp0 + (size_t)32 * S);  // V[kk][d=32+l31]
      } else {
        const float* vp = v + ((size_t)bh * S + kb2 + s2 * 16 + hi * 8) * D + l31;
#pragma unroll
        for (int e = 0; e < 8; ++e) {
          vf0[e] = (short)f2bf(vp[(size_t)e * D]);
          vf1[e] = (short)f2bf(vp[(size_t)e * D + 32]);
        }
      }
      oacc0 = __builtin_amdgcn_mfma_f32_32x32x16_bf16(pa, vf0, oacc0, 0, 0, 0);
      oacc1 = __builtin_amdgcn_mfma_f32_32x32x16_bf16(pa, vf1, oacc1, 0, 0, 0);
    }
  }

  float* oh = outp + (size_t)bh * S * D;
#pragma unroll
  for (int r = 0; r < 16; ++r) {
    int ql = (r & 3) + 8 * (r >> 2) + 4 * hi;
    oh[(size_t)(qb + ql) * D + l31] = oacc0[r];
    oh[(size_t)(qb + ql) * D + 32 + l31] = oacc1[r];
  }
}

extern "C" void kernel_launch(void* const* d_in, const int* in_sizes, int n_in,
                              void* d_out, int out_size, void* d_ws, size_t ws_size,
                              hipStream_t stream) {
  const float* q = (const float*)d_in[0];
  const float* k = (const float*)d_in[1];
  const float* v = (const float*)d_in[2];
  const int* mask = (const int*)d_in[3];
  float* outp = (float*)d_out;
  float* attnp = outp + (size_t)BH * S * D;  // out first, then attn
  float* rcp = (float*)d_ws;                 // 256 KB
  size_t rcp_bytes = (size_t)BH * S * 4;
  size_t packed_bytes = (size_t)BH * 32 * S * 4;  // 8.4 MB
  size_t bf_bytes = (size_t)BH * S * D * 2;       // 8.4 MB each

  unsigned* packed = (unsigned*)((char*)d_ws + rcp_bytes);
  unsigned short* qbf = (unsigned short*)((char*)d_ws + rcp_bytes + packed_bytes);
  unsigned short* kbf = qbf + (size_t)BH * S * D;
  unsigned short* vt = kbf + (size_t)BH * S * D;

  if (ws_size >= rcp_bytes + packed_bytes + 3 * bf_bytes) {
    cvt_kernel<<<dim3(1024, 2), 256, 0, stream>>>(q, k, qbf, kbf);
    vt_kernel<<<dim3(16, BH), 256, 0, stream>>>(v, vt);
    colsum_kernel<true, true><<<dim3(S / 32, BH), 256, 0, stream>>>(
        q, k, qbf, kbf, mask, rcp, packed);
    attn_out_kernel<true, true><<<dim3(S / 128, BH), 256, 0, stream>>>(
        q, k, v, qbf, kbf, vt, mask, packed, rcp, outp, attnp);
  } else if (ws_size >= rcp_bytes + packed_bytes) {
    colsum_kernel<false, true><<<dim3(S / 32, BH), 256, 0, stream>>>(
        q, k, nullptr, nullptr, mask, rcp, packed);
    attn_out_kernel<false, true><<<dim3(S / 128, BH), 256, 0, stream>>>(
        q, k, v, nullptr, nullptr, nullptr, mask, packed, rcp, outp, attnp);
  } else {
    colsum_kernel<false, false><<<dim3(S / 32, BH), 256, 0, stream>>>(
        q, k, nullptr, nullptr, mask, rcp, nullptr);
    attn_out_kernel<false, false><<<dim3(S / 128, BH), 256, 0, stream>>>(
        q, k, v, nullptr, nullptr, nullptr, mask, nullptr, rcp, outp, attnp);
  }
}

// Round 7
// 250.319 us; speedup vs baseline: 1.9961x; 1.0024x over previous
//
#include <hip/hip_runtime.h>
#include <hip/hip_bf16.h>

#define S 1024
#define D 64
#define BH 64
#define SCALE 0.125f

typedef __attribute__((ext_vector_type(8))) short short8;
typedef __attribute__((ext_vector_type(16))) float f32x16;

// fp32 -> bf16 RNE. Plain bit ops, NO inline asm (asm cvt_pk measured ~2x
// slower in rounds 2-4; matches learn_hip m240).
static __device__ __forceinline__ unsigned short f2bf(float f) {
  union { float f; unsigned u; } v; v.f = f;
  return (unsigned short)((v.u + 0x7fffu + ((v.u >> 16) & 1u)) >> 16);
}

static __device__ __forceinline__ short8 load_frag8_f32(const float* p) {
  float4 a = *(const float4*)p;
  float4 b = *(const float4*)(p + 4);
  short8 r;
  r[0] = f2bf(a.x); r[1] = f2bf(a.y); r[2] = f2bf(a.z); r[3] = f2bf(a.w);
  r[4] = f2bf(b.x); r[5] = f2bf(b.y); r[6] = f2bf(b.z); r[7] = f2bf(b.w);
  return r;
}

// Pre-pass A: q,k fp32 -> bf16 straight convert.
__global__ __launch_bounds__(256) void cvt_kernel(
    const float* __restrict__ s0, const float* __restrict__ s1,
    unsigned short* __restrict__ d0, unsigned short* __restrict__ d1) {
  const float* s = blockIdx.y == 0 ? s0 : s1;
  unsigned short* d = blockIdx.y == 0 ? d0 : d1;
  size_t i = (size_t)(blockIdx.x * 256 + threadIdx.x) * 8;
#pragma unroll
  for (int c = 0; c < 2; ++c, i += (size_t)1024 * 256 * 8)
    *(short8*)(d + i) = load_frag8_f32(s + i);
}

// Pre-pass B: v fp32 [bh][s][d] -> vT bf16 [bh][d][s] via 64x64 LDS tile.
__global__ __launch_bounds__(256) void vt_kernel(
    const float* __restrict__ v, unsigned short* __restrict__ vt) {
  __shared__ float t[64][65];
  int bh = blockIdx.y;
  int s0 = blockIdx.x * 64;
  int tid = threadIdx.x;
  {
    int r = tid >> 2, c4 = (tid & 3) * 16;
    const float4* src = (const float4*)(v + ((size_t)bh * S + s0 + r) * D + c4);
#pragma unroll
    for (int j = 0; j < 4; ++j) {
      float4 x = src[j];
      t[r][c4 + j * 4 + 0] = x.x; t[r][c4 + j * 4 + 1] = x.y;
      t[r][c4 + j * 4 + 2] = x.z; t[r][c4 + j * 4 + 3] = x.w;
    }
  }
  __syncthreads();
  {
    int d = tid >> 2, sc = (tid & 3) * 16;
    unsigned short* dst = vt + ((size_t)bh * D + d) * S + s0 + sc;
    short8 o0, o1;
#pragma unroll
    for (int j = 0; j < 8; ++j) {
      o0[j] = (short)f2bf(t[sc + j][d]);
      o1[j] = (short)f2bf(t[sc + 8 + j][d]);
    }
    *(short8*)dst = o0;
    *(short8*)(dst + 8) = o1;
  }
}

// Phase 1: rcp[bh,kcol] = 1/sum_q exp(masked score) + mask bit-pack
// packed[bh][qrow>>5][kcol] bit (qrow&31). Round-1 structure.
template <bool PRE, bool PACK>
__global__ __launch_bounds__(256) void colsum_kernel(
    const float* __restrict__ q, const float* __restrict__ k,
    const unsigned short* __restrict__ qbf, const unsigned short* __restrict__ kbf,
    const int* __restrict__ mask, float* __restrict__ rcp,
    unsigned* __restrict__ packed) {
  int tid = threadIdx.x;
  int wave = tid >> 6, lane = tid & 63;
  int l31 = lane & 31, hi = lane >> 5;
  int kb = blockIdx.x * 32;
  int bh = blockIdx.y;
  const int* mh = mask + (size_t)bh * S * S;

  short8 bfrag[4];
  if (PRE) {
    const unsigned short* kp = kbf + ((size_t)bh * S + kb + l31) * D + hi * 8;
#pragma unroll
    for (int s = 0; s < 4; ++s) bfrag[s] = *(const short8*)(kp + s * 16);
  } else {
    const float* kp = k + ((size_t)bh * S + kb + l31) * D + hi * 8;
#pragma unroll
    for (int s = 0; s < 4; ++s) bfrag[s] = load_frag8_f32(kp + s * 16);
  }

  int kcol = kb + l31;
  float colpart = 0.f;
  for (int it = 0; it < 8; ++it) {
    int q0 = it * 128 + wave * 32;  // one 32-row q-word: index it*4+wave
    short8 afrag[4];
    if (PRE) {
      const unsigned short* qp = qbf + ((size_t)bh * S + q0 + l31) * D + hi * 8;
#pragma unroll
      for (int s = 0; s < 4; ++s) afrag[s] = *(const short8*)(qp + s * 16);
    } else {
      const float* qp = q + ((size_t)bh * S + q0 + l31) * D + hi * 8;
#pragma unroll
      for (int s = 0; s < 4; ++s) afrag[s] = load_frag8_f32(qp + s * 16);
    }
    f32x16 acc = {};
#pragma unroll
    for (int s = 0; s < 4; ++s)
      acc = __builtin_amdgcn_mfma_f32_32x32x16_bf16(afrag[s], bfrag[s], acc, 0, 0, 0);

    unsigned w = 0;
#pragma unroll
    for (int r = 0; r < 16; ++r) {
      int crow0 = (r & 3) + 8 * (r >> 2);
      int qrow = q0 + crow0 + 4 * hi;
      int m = mh[(size_t)qrow * S + kcol];
      if (PACK) w |= (m ? 1u : 0u) << (crow0 + 4 * hi);
      colpart += m ? __expf(acc[r] * SCALE) : 0.0f;
    }
    if (PACK) {
      w |= __shfl_xor(w, 32, 64);
      if (lane < 32) {
        int qw = it * 4 + wave;
        packed[((size_t)bh * 32 + qw) * S + kb + l31] = w;  // 128B coalesced
      }
    }
  }
  colpart += __shfl_xor(colpart, 32, 64);
  __shared__ float red[4][32];
  if (lane < 32) red[wave][lane] = colpart;
  __syncthreads();
  if (tid < 32) {
    float t = red[0][tid] + red[1][tid] + red[2][tid] + red[3][tid];
    rcp[(size_t)bh * S + kb + tid] = 1.0f / t;
  }
}

// Phase 2: 1024 blocks x 4 waves. Block owns 64 q-rows; wave w handles
// q-tile (w>>1) and k-half (w&1) => 16 k-tiles each, 4 waves/SIMD.
// out partials for the two k-halves folded via padded-LDS epilogue.
template <bool PRE, bool PACKED>
__global__ __launch_bounds__(256, 4) void attn_out_kernel(
    const float* __restrict__ q, const float* __restrict__ k,
    const float* __restrict__ v, const unsigned short* __restrict__ qbf,
    const unsigned short* __restrict__ kbf, const unsigned short* __restrict__ vt,
    const int* __restrict__ mask, const unsigned* __restrict__ packed,
    const float* __restrict__ rcp, float* __restrict__ outp,
    float* __restrict__ attnp) {
  int tid = threadIdx.x;
  int wave = tid >> 6, lane = tid & 63;
  int l31 = lane & 31, hi = lane >> 5;
  int qt = wave >> 1, kh = wave & 1;
  int bh = blockIdx.y;
  int qb = blockIdx.x * 64 + qt * 32;
  int qword = blockIdx.x * 2 + qt;      // qb>>5
  const int* mh = mask + (size_t)bh * S * S;
  const float* rch = rcp + (size_t)bh * S;
  float* ah = attnp + (size_t)bh * S * S;
  const unsigned short* vtb = PRE ? vt + (size_t)bh * D * S : nullptr;

  __shared__ float sm[4][32][33];    // per-wave P tile, +1 pad (16.9 KB)
  __shared__ unsigned wlds[2][1024]; // [q-tile][kcol] packed mask (8 KB)

  if (PACKED) {
    const int4* src = (const int4*)(packed + ((size_t)bh * 32 + blockIdx.x * 2) * S);
    int4* dst = (int4*)&wlds[0][0];
#pragma unroll
    for (int j = 0; j < 2; ++j) dst[tid + j * 256] = src[tid + j * 256];
    __syncthreads();
  }

  short8 afrag[4];
  if (PRE) {
    const unsigned short* qp = qbf + ((size_t)bh * S + qb + l31) * D + hi * 8;
#pragma unroll
    for (int s = 0; s < 4; ++s) afrag[s] = *(const short8*)(qp + s * 16);
  } else {
    const float* qp = q + ((size_t)bh * S + qb + l31) * D + hi * 8;
#pragma unroll
    for (int s = 0; s < 4; ++s) afrag[s] = load_frag8_f32(qp + s * 16);
  }

  f32x16 oacc0 = {}, oacc1 = {};

  for (int t = 0; t < 16; ++t) {
    int kt = kh * 16 + t;
    int kb2 = kt * 32;
    short8 bfrag[4];
    if (PRE) {
      const unsigned short* kp = kbf + ((size_t)bh * S + kb2 + l31) * D + hi * 8;
#pragma unroll
      for (int s = 0; s < 4; ++s) bfrag[s] = *(const short8*)(kp + s * 16);
    } else {
      const float* kp = k + ((size_t)bh * S + kb2 + l31) * D + hi * 8;
#pragma unroll
      for (int s = 0; s < 4; ++s) bfrag[s] = load_frag8_f32(kp + s * 16);
    }
    f32x16 acc = {};
#pragma unroll
    for (int s = 0; s < 4; ++s)
      acc = __builtin_amdgcn_mfma_f32_32x32x16_bf16(afrag[s], bfrag[s], acc, 0, 0, 0);

    int kcol = kb2 + l31;
    float rc = rch[kcol];
    unsigned mw = PACKED ? wlds[qt][kcol] : 0u;
#pragma unroll
    for (int r = 0; r < 16; ++r) {
      int ql = (r & 3) + 8 * (r >> 2) + 4 * hi;
      int qrow = qb + ql;
      unsigned bit;
      if (PACKED) bit = (mw >> ql) & 1u;
      else        bit = mh[(size_t)qrow * S + kcol] ? 1u : 0u;
      float e = bit ? __expf(acc[r] * SCALE) * rc : 0.0f;
      ah[(size_t)qrow * S + kcol] = e;
      sm[wave][ql][l31] = e;
    }

    // PV: out[q][d] += P[q][kk] * v[kk][d]
#pragma unroll
    for (int s2 = 0; s2 < 2; ++s2) {
      short8 pa;
      const float* smrow = &sm[wave][l31][0];
#pragma unroll
      for (int e = 0; e < 8; ++e) pa[e] = (short)f2bf(smrow[s2 * 16 + hi * 8 + e]);
      short8 vf0, vf1;
      if (PRE) {
        const unsigned short* vp0 = vtb + (size_t)l31 * S + kb2 + s2 * 16 + hi * 8;
        vf0 = *(const short8*)vp0;                     // V[kk][d=l31]
        vf1 = *(const short8*)(vp0 + (size_t)32 * S);  // V[kk][d=32+l31]
      } else {
        const float* vp = v + ((size_t)bh * S + kb2 + s2 * 16 + hi * 8) * D + l31;
#pragma unroll
        for (int e = 0; e < 8; ++e) {
          vf0[e] = (short)f2bf(vp[(size_t)e * D]);
          vf1[e] = (short)f2bf(vp[(size_t)e * D + 32]);
        }
      }
      oacc0 = __builtin_amdgcn_mfma_f32_32x32x16_bf16(pa, vf0, oacc0, 0, 0, 0);
      oacc1 = __builtin_amdgcn_mfma_f32_32x32x16_bf16(pa, vf1, oacc1, 0, 0, 0);
    }
  }

  // fold k-halves: odd waves dump to padded LDS, even waves add + store.
  __syncthreads();
  float* buf = &sm[0][0][0];  // 4224 floats; need 2*64*33 = 4224 exactly
  if (kh == 1) {
    float* dst = buf + (size_t)qt * 2112 + lane * 33;
#pragma unroll
    for (int r = 0; r < 16; ++r) { dst[r] = oacc0[r]; dst[16 + r] = oacc1[r]; }
  }
  __syncthreads();
  if (kh == 0) {
    const float* src = buf + (size_t)qt * 2112 + lane * 33;
    float* oh = outp + (size_t)bh * S * D;
#pragma unroll
    for (int r = 0; r < 16; ++r) {
      int ql = (r & 3) + 8 * (r >> 2) + 4 * hi;
      oh[(size_t)(qb + ql) * D + l31] = oacc0[r] + src[r];
      oh[(size_t)(qb + ql) * D + 32 + l31] = oacc1[r] + src[16 + r];
    }
  }
}

extern "C" void kernel_launch(void* const* d_in, const int* in_sizes, int n_in,
                              void* d_out, int out_size, void* d_ws, size_t ws_size,
                              hipStream_t stream) {
  const float* q = (const float*)d_in[0];
  const float* k = (const float*)d_in[1];
  const float* v = (const float*)d_in[2];
  const int* mask = (const int*)d_in[3];
  float* outp = (float*)d_out;
  float* attnp = outp + (size_t)BH * S * D;  // out first, then attn
  float* rcp = (float*)d_ws;                 // 256 KB
  size_t rcp_bytes = (size_t)BH * S * 4;
  size_t packed_bytes = (size_t)BH * 32 * S * 4;  // 8.4 MB
  size_t bf_bytes = (size_t)BH * S * D * 2;       // 8.4 MB each

  unsigned* packed = (unsigned*)((char*)d_ws + rcp_bytes);
  unsigned short* qbf = (unsigned short*)((char*)d_ws + rcp_bytes + packed_bytes);
  unsigned short* kbf = qbf + (size_t)BH * S * D;
  unsigned short* vt = kbf + (size_t)BH * S * D;

  if (ws_size >= rcp_bytes + packed_bytes + 3 * bf_bytes) {
    cvt_kernel<<<dim3(1024, 2), 256, 0, stream>>>(q, k, qbf, kbf);
    vt_kernel<<<dim3(16, BH), 256, 0, stream>>>(v, vt);
    colsum_kernel<true, true><<<dim3(S / 32, BH), 256, 0, stream>>>(
        q, k, qbf, kbf, mask, rcp, packed);
    attn_out_kernel<true, true><<<dim3(S / 64, BH), 256, 0, stream>>>(
        q, k, v, qbf, kbf, vt, mask, packed, rcp, outp, attnp);
  } else if (ws_size >= rcp_bytes + packed_bytes) {
    colsum_kernel<false, true><<<dim3(S / 32, BH), 256, 0, stream>>>(
        q, k, nullptr, nullptr, mask, rcp, packed);
    attn_out_kernel<false, true><<<dim3(S / 64, BH), 256, 0, stream>>>(
        q, k, v, nullptr, nullptr, nullptr, mask, packed, rcp, outp, attnp);
  } else {
    colsum_kernel<false, false><<<dim3(S / 32, BH), 256, 0, stream>>>(
        q, k, nullptr, nullptr, mask, rcp, nullptr);
    attn_out_kernel<false, false><<<dim3(S / 64, BH), 256, 0, stream>>>(
        q, k, v, nullptr, nullptr, nullptr, mask, nullptr, rcp, outp, attnp);
  }
}

// Round 8
// 242.396 us; speedup vs baseline: 2.0614x; 1.0327x over previous
//
#include <hip/hip_runtime.h>
#include <hip/hip_bf16.h>

#define S 1024
#define D 64
#define BH 64
#define SCALE 0.125f

typedef __attribute__((ext_vector_type(8))) short short8;
typedef __attribute__((ext_vector_type(16))) float f32x16;

// fp32 -> bf16 RNE. Plain bit ops, NO inline asm (asm cvt_pk measured ~2x
// slower in rounds 2-4; matches learn_hip m240).
static __device__ __forceinline__ unsigned short f2bf(float f) {
  union { float f; unsigned u; } v; v.f = f;
  return (unsigned short)((v.u + 0x7fffu + ((v.u >> 16) & 1u)) >> 16);
}

static __device__ __forceinline__ short8 load_frag8_f32(const float* p) {
  float4 a = *(const float4*)p;
  float4 b = *(const float4*)(p + 4);
  short8 r;
  r[0] = f2bf(a.x); r[1] = f2bf(a.y); r[2] = f2bf(a.z); r[3] = f2bf(a.w);
  r[4] = f2bf(b.x); r[5] = f2bf(b.y); r[6] = f2bf(b.z); r[7] = f2bf(b.w);
  return r;
}

// Pre-pass A: q,k fp32 -> bf16 straight convert.
__global__ __launch_bounds__(256) void cvt_kernel(
    const float* __restrict__ s0, const float* __restrict__ s1,
    unsigned short* __restrict__ d0, unsigned short* __restrict__ d1) {
  const float* s = blockIdx.y == 0 ? s0 : s1;
  unsigned short* d = blockIdx.y == 0 ? d0 : d1;
  size_t i = (size_t)(blockIdx.x * 256 + threadIdx.x) * 8;
#pragma unroll
  for (int c = 0; c < 2; ++c, i += (size_t)1024 * 256 * 8)
    *(short8*)(d + i) = load_frag8_f32(s + i);
}

// Pre-pass B: v fp32 [bh][s][d] -> vT bf16 [bh][d][s] via 64x64 LDS tile.
__global__ __launch_bounds__(256) void vt_kernel(
    const float* __restrict__ v, unsigned short* __restrict__ vt) {
  __shared__ float t[64][65];
  int bh = blockIdx.y;
  int s0 = blockIdx.x * 64;
  int tid = threadIdx.x;
  {
    int r = tid >> 2, c4 = (tid & 3) * 16;
    const float4* src = (const float4*)(v + ((size_t)bh * S + s0 + r) * D + c4);
#pragma unroll
    for (int j = 0; j < 4; ++j) {
      float4 x = src[j];
      t[r][c4 + j * 4 + 0] = x.x; t[r][c4 + j * 4 + 1] = x.y;
      t[r][c4 + j * 4 + 2] = x.z; t[r][c4 + j * 4 + 3] = x.w;
    }
  }
  __syncthreads();
  {
    int d = tid >> 2, sc = (tid & 3) * 16;
    unsigned short* dst = vt + ((size_t)bh * D + d) * S + s0 + sc;
    short8 o0, o1;
#pragma unroll
    for (int j = 0; j < 8; ++j) {
      o0[j] = (short)f2bf(t[sc + j][d]);
      o1[j] = (short)f2bf(t[sc + 8 + j][d]);
    }
    *(short8*)dst = o0;
    *(short8*)(dst + 8) = o1;
  }
}

// Phase 1: rcp[bh,kcol] = 1/sum_q exp(masked score) + mask bit-pack.
// 1D grid 2048, XCD-swizzled: all 32 k-blocks of a bh on ONE XCD so the
// bh's qbf (128 KB) stays L2-resident (8 bh x 128 KB = 1 MB per XCD).
template <bool PRE, bool PACK>
__global__ __launch_bounds__(256) void colsum_kernel(
    const float* __restrict__ q, const float* __restrict__ k,
    const unsigned short* __restrict__ qbf, const unsigned short* __restrict__ kbf,
    const int* __restrict__ mask, float* __restrict__ rcp,
    unsigned* __restrict__ packed) {
  int tid = threadIdx.x;
  int wave = tid >> 6, lane = tid & 63;
  int l31 = lane & 31, hi = lane >> 5;
  int d0 = blockIdx.x;
  int xcd = d0 & 7, idx = d0 >> 3;       // HW round-robins d%8 across XCDs
  int bh = xcd * 8 + (idx >> 5);         // 8 bh per XCD, contiguous in time
  int kbi = idx & 31;
  int kb = kbi * 32;
  const int* mh = mask + (size_t)bh * S * S;

  short8 bfrag[4];
  if (PRE) {
    const unsigned short* kp = kbf + ((size_t)bh * S + kb + l31) * D + hi * 8;
#pragma unroll
    for (int s = 0; s < 4; ++s) bfrag[s] = *(const short8*)(kp + s * 16);
  } else {
    const float* kp = k + ((size_t)bh * S + kb + l31) * D + hi * 8;
#pragma unroll
    for (int s = 0; s < 4; ++s) bfrag[s] = load_frag8_f32(kp + s * 16);
  }

  int kcol = kb + l31;
  float colpart = 0.f;
  for (int it = 0; it < 8; ++it) {
    int q0 = it * 128 + wave * 32;  // one 32-row q-word: index it*4+wave
    short8 afrag[4];
    if (PRE) {
      const unsigned short* qp = qbf + ((size_t)bh * S + q0 + l31) * D + hi * 8;
#pragma unroll
      for (int s = 0; s < 4; ++s) afrag[s] = *(const short8*)(qp + s * 16);
    } else {
      const float* qp = q + ((size_t)bh * S + q0 + l31) * D + hi * 8;
#pragma unroll
      for (int s = 0; s < 4; ++s) afrag[s] = load_frag8_f32(qp + s * 16);
    }
    f32x16 acc = {};
#pragma unroll
    for (int s = 0; s < 4; ++s)
      acc = __builtin_amdgcn_mfma_f32_32x32x16_bf16(afrag[s], bfrag[s], acc, 0, 0, 0);

    unsigned w = 0;
#pragma unroll
    for (int r = 0; r < 16; ++r) {
      int crow0 = (r & 3) + 8 * (r >> 2);
      int qrow = q0 + crow0 + 4 * hi;
      int m = mh[(size_t)qrow * S + kcol];
      if (PACK) w |= (m ? 1u : 0u) << (crow0 + 4 * hi);
      colpart += m ? __expf(acc[r] * SCALE) : 0.0f;
    }
    if (PACK) {
      w |= __shfl_xor(w, 32, 64);
      if (lane < 32) {
        int qw = it * 4 + wave;
        packed[((size_t)bh * 32 + qw) * S + kb + l31] = w;  // 128B coalesced
      }
    }
  }
  colpart += __shfl_xor(colpart, 32, 64);
  __shared__ float red[4][32];
  if (lane < 32) red[wave][lane] = colpart;
  __syncthreads();
  if (tid < 32) {
    float t = red[0][tid] + red[1][tid] + red[2][tid] + red[3][tid];
    rcp[(size_t)bh * S + kb + tid] = 1.0f / t;
  }
}

// Phase 2 (round-6 structure): 512 blocks x 4 waves, wave owns 32 q-rows,
// full k-sweep. 1D grid, XCD-swizzled: the 8 q-blocks of a bh share one
// XCD so k/vT (256 KB per bh, 2 MB per XCD) are L2-hits, not HBM.
template <bool PRE, bool PACKED>
__global__ __launch_bounds__(256) void attn_out_kernel(
    const float* __restrict__ q, const float* __restrict__ k,
    const float* __restrict__ v, const unsigned short* __restrict__ qbf,
    const unsigned short* __restrict__ kbf, const unsigned short* __restrict__ vt,
    const int* __restrict__ mask, const unsigned* __restrict__ packed,
    const float* __restrict__ rcp, float* __restrict__ outp,
    float* __restrict__ attnp) {
  int tid = threadIdx.x;
  int wave = tid >> 6, lane = tid & 63;
  int l31 = lane & 31, hi = lane >> 5;
  int d0 = blockIdx.x;
  int xcd = d0 & 7, idx = d0 >> 3;
  int bh = xcd * 8 + (idx >> 3);        // 8 bh per XCD
  int qblk = idx & 7;
  int qb = qblk * 128 + wave * 32;
  const int* mh = mask + (size_t)bh * S * S;
  const float* rch = rcp + (size_t)bh * S;
  float* ah = attnp + (size_t)bh * S * S;
  const unsigned short* vtb = PRE ? vt + (size_t)bh * D * S : nullptr;

  __shared__ float sm[4][32][33];    // per-wave P tile, +1 pad
  __shared__ unsigned wlds[4][1024]; // [q-word][kcol] packed mask

  if (PACKED) {
    const int4* src = (const int4*)(packed + ((size_t)bh * 32 + qblk * 4) * S);
    int4* dst = (int4*)&wlds[0][0];
#pragma unroll
    for (int j = 0; j < 4; ++j) dst[tid + j * 256] = src[tid + j * 256];
    __syncthreads();
  }

  short8 afrag[4];
  if (PRE) {
    const unsigned short* qp = qbf + ((size_t)bh * S + qb + l31) * D + hi * 8;
#pragma unroll
    for (int s = 0; s < 4; ++s) afrag[s] = *(const short8*)(qp + s * 16);
  } else {
    const float* qp = q + ((size_t)bh * S + qb + l31) * D + hi * 8;
#pragma unroll
    for (int s = 0; s < 4; ++s) afrag[s] = load_frag8_f32(qp + s * 16);
  }

  f32x16 oacc0 = {}, oacc1 = {};

  for (int kt = 0; kt < 32; ++kt) {
    int kb2 = kt * 32;
    short8 bfrag[4];
    if (PRE) {
      const unsigned short* kp = kbf + ((size_t)bh * S + kb2 + l31) * D + hi * 8;
#pragma unroll
      for (int s = 0; s < 4; ++s) bfrag[s] = *(const short8*)(kp + s * 16);
    } else {
      const float* kp = k + ((size_t)bh * S + kb2 + l31) * D + hi * 8;
#pragma unroll
      for (int s = 0; s < 4; ++s) bfrag[s] = load_frag8_f32(kp + s * 16);
    }
    f32x16 acc = {};
#pragma unroll
    for (int s = 0; s < 4; ++s)
      acc = __builtin_amdgcn_mfma_f32_32x32x16_bf16(afrag[s], bfrag[s], acc, 0, 0, 0);

    int kcol = kb2 + l31;
    float rc = rch[kcol];
    unsigned mw = PACKED ? wlds[wave][kcol] : 0u;
#pragma unroll
    for (int r = 0; r < 16; ++r) {
      int ql = (r & 3) + 8 * (r >> 2) + 4 * hi;
      int qrow = qb + ql;
      unsigned bit;
      if (PACKED) bit = (mw >> ql) & 1u;
      else        bit = mh[(size_t)qrow * S + kcol] ? 1u : 0u;
      float e = bit ? __expf(acc[r] * SCALE) * rc : 0.0f;
      ah[(size_t)qrow * S + kcol] = e;
      sm[wave][ql][l31] = e;
    }

    // PV: out[q][d] += P[q][kk] * v[kk][d]
#pragma unroll
    for (int s2 = 0; s2 < 2; ++s2) {
      short8 pa;
      const float* smrow = &sm[wave][l31][0];
#pragma unroll
      for (int e = 0; e < 8; ++e) pa[e] = (short)f2bf(smrow[s2 * 16 + hi * 8 + e]);
      short8 vf0, vf1;
      if (PRE) {
        const unsigned short* vp0 = vtb + (size_t)l31 * S + kb2 + s2 * 16 + hi * 8;
        vf0 = *(const short8*)vp0;                     // V[kk][d=l31]
        vf1 = *(const short8*)(vp0 + (size_t)32 * S);  // V[kk][d=32+l31]
      } else {
        const float* vp = v + ((size_t)bh * S + kb2 + s2 * 16 + hi * 8) * D + l31;
#pragma unroll
        for (int e = 0; e < 8; ++e) {
          vf0[e] = (short)f2bf(vp[(size_t)e * D]);
          vf1[e] = (short)f2bf(vp[(size_t)e * D + 32]);
        }
      }
      oacc0 = __builtin_amdgcn_mfma_f32_32x32x16_bf16(pa, vf0, oacc0, 0, 0, 0);
      oacc1 = __builtin_amdgcn_mfma_f32_32x32x16_bf16(pa, vf1, oacc1, 0, 0, 0);
    }
  }

  float* oh = outp + (size_t)bh * S * D;
#pragma unroll
  for (int r = 0; r < 16; ++r) {
    int ql = (r & 3) + 8 * (r >> 2) + 4 * hi;
    oh[(size_t)(qb + ql) * D + l31] = oacc0[r];
    oh[(size_t)(qb + ql) * D + 32 + l31] = oacc1[r];
  }
}

extern "C" void kernel_launch(void* const* d_in, const int* in_sizes, int n_in,
                              void* d_out, int out_size, void* d_ws, size_t ws_size,
                              hipStream_t stream) {
  const float* q = (const float*)d_in[0];
  const float* k = (const float*)d_in[1];
  const float* v = (const float*)d_in[2];
  const int* mask = (const int*)d_in[3];
  float* outp = (float*)d_out;
  float* attnp = outp + (size_t)BH * S * D;  // out first, then attn
  float* rcp = (float*)d_ws;                 // 256 KB
  size_t rcp_bytes = (size_t)BH * S * 4;
  size_t packed_bytes = (size_t)BH * 32 * S * 4;  // 8.4 MB
  size_t bf_bytes = (size_t)BH * S * D * 2;       // 8.4 MB each

  unsigned* packed = (unsigned*)((char*)d_ws + rcp_bytes);
  unsigned short* qbf = (unsigned short*)((char*)d_ws + rcp_bytes + packed_bytes);
  unsigned short* kbf = qbf + (size_t)BH * S * D;
  unsigned short* vt = kbf + (size_t)BH * S * D;

  if (ws_size >= rcp_bytes + packed_bytes + 3 * bf_bytes) {
    cvt_kernel<<<dim3(1024, 2), 256, 0, stream>>>(q, k, qbf, kbf);
    vt_kernel<<<dim3(16, BH), 256, 0, stream>>>(v, vt);
    colsum_kernel<true, true><<<2048, 256, 0, stream>>>(
        q, k, qbf, kbf, mask, rcp, packed);
    attn_out_kernel<true, true><<<512, 256, 0, stream>>>(
        q, k, v, qbf, kbf, vt, mask, packed, rcp, outp, attnp);
  } else if (ws_size >= rcp_bytes + packed_bytes) {
    colsum_kernel<false, true><<<2048, 256, 0, stream>>>(
        q, k, nullptr, nullptr, mask, rcp, packed);
    attn_out_kernel<false, true><<<512, 256, 0, stream>>>(
        q, k, v, nullptr, nullptr, nullptr, mask, packed, rcp, outp, attnp);
  } else {
    colsum_kernel<false, false><<<2048, 256, 0, stream>>>(
        q, k, nullptr, nullptr, mask, rcp, nullptr);
    attn_out_kernel<false, false><<<512, 256, 0, stream>>>(
        q, k, v, nullptr, nullptr, nullptr, mask, nullptr, rcp, outp, attnp);
  }
}

// Round 9
// 241.682 us; speedup vs baseline: 2.0675x; 1.0030x over previous
//
#include <hip/hip_runtime.h>
#include <hip/hip_bf16.h>

#define S 1024
#define D 64
#define BH 64
#define SCALE 0.125f

typedef __attribute__((ext_vector_type(8))) short short8;
typedef __attribute__((ext_vector_type(4))) short s4v;
typedef __attribute__((ext_vector_type(16))) float f32x16;

// fp32 -> bf16 RNE. Plain bit ops, NO inline asm (asm cvt_pk measured ~2x
// slower in rounds 2-4; matches learn_hip m240).
static __device__ __forceinline__ unsigned short f2bf(float f) {
  union { float f; unsigned u; } v; v.f = f;
  return (unsigned short)((v.u + 0x7fffu + ((v.u >> 16) & 1u)) >> 16);
}

static __device__ __forceinline__ float bf2f(unsigned short h) {
  union { unsigned u; float f; } v; v.u = (unsigned)h << 16; return v.f;
}

static __device__ __forceinline__ short8 load_frag8_f32(const float* p) {
  float4 a = *(const float4*)p;
  float4 b = *(const float4*)(p + 4);
  short8 r;
  r[0] = f2bf(a.x); r[1] = f2bf(a.y); r[2] = f2bf(a.z); r[3] = f2bf(a.w);
  r[4] = f2bf(b.x); r[5] = f2bf(b.y); r[6] = f2bf(b.z); r[7] = f2bf(b.w);
  return r;
}

// Pre-pass A: q,k fp32 -> bf16 straight convert.
__global__ __launch_bounds__(256) void cvt_kernel(
    const float* __restrict__ s0, const float* __restrict__ s1,
    unsigned short* __restrict__ d0, unsigned short* __restrict__ d1) {
  const float* s = blockIdx.y == 0 ? s0 : s1;
  unsigned short* d = blockIdx.y == 0 ? d0 : d1;
  size_t i = (size_t)(blockIdx.x * 256 + threadIdx.x) * 8;
#pragma unroll
  for (int c = 0; c < 2; ++c, i += (size_t)1024 * 256 * 8)
    *(short8*)(d + i) = load_frag8_f32(s + i);
}

// Pre-pass B: v fp32 [bh][s][d] -> vT bf16 [bh][d][s] via 64x64 LDS tile.
__global__ __launch_bounds__(256) void vt_kernel(
    const float* __restrict__ v, unsigned short* __restrict__ vt) {
  __shared__ float t[64][65];
  int bh = blockIdx.y;
  int s0 = blockIdx.x * 64;
  int tid = threadIdx.x;
  {
    int r = tid >> 2, c4 = (tid & 3) * 16;
    const float4* src = (const float4*)(v + ((size_t)bh * S + s0 + r) * D + c4);
#pragma unroll
    for (int j = 0; j < 4; ++j) {
      float4 x = src[j];
      t[r][c4 + j * 4 + 0] = x.x; t[r][c4 + j * 4 + 1] = x.y;
      t[r][c4 + j * 4 + 2] = x.z; t[r][c4 + j * 4 + 3] = x.w;
    }
  }
  __syncthreads();
  {
    int d = tid >> 2, sc = (tid & 3) * 16;
    unsigned short* dst = vt + ((size_t)bh * D + d) * S + s0 + sc;
    short8 o0, o1;
#pragma unroll
    for (int j = 0; j < 8; ++j) {
      o0[j] = (short)f2bf(t[sc + j][d]);
      o1[j] = (short)f2bf(t[sc + 8 + j][d]);
    }
    *(short8*)dst = o0;
    *(short8*)(dst + 8) = o1;
  }
}

// Phase 1 (unchanged from round 8): rcp + packed mask, XCD-swizzled.
template <bool PRE, bool PACK>
__global__ __launch_bounds__(256) void colsum_kernel(
    const float* __restrict__ q, const float* __restrict__ k,
    const unsigned short* __restrict__ qbf, const unsigned short* __restrict__ kbf,
    const int* __restrict__ mask, float* __restrict__ rcp,
    unsigned* __restrict__ packed) {
  int tid = threadIdx.x;
  int wave = tid >> 6, lane = tid & 63;
  int l31 = lane & 31, hi = lane >> 5;
  int d0 = blockIdx.x;
  int xcd = d0 & 7, idx = d0 >> 3;
  int bh = xcd * 8 + (idx >> 5);
  int kbi = idx & 31;
  int kb = kbi * 32;
  const int* mh = mask + (size_t)bh * S * S;

  short8 bfrag[4];
  if (PRE) {
    const unsigned short* kp = kbf + ((size_t)bh * S + kb + l31) * D + hi * 8;
#pragma unroll
    for (int s = 0; s < 4; ++s) bfrag[s] = *(const short8*)(kp + s * 16);
  } else {
    const float* kp = k + ((size_t)bh * S + kb + l31) * D + hi * 8;
#pragma unroll
    for (int s = 0; s < 4; ++s) bfrag[s] = load_frag8_f32(kp + s * 16);
  }

  int kcol = kb + l31;
  float colpart = 0.f;
  for (int it = 0; it < 8; ++it) {
    int q0 = it * 128 + wave * 32;
    short8 afrag[4];
    if (PRE) {
      const unsigned short* qp = qbf + ((size_t)bh * S + q0 + l31) * D + hi * 8;
#pragma unroll
      for (int s = 0; s < 4; ++s) afrag[s] = *(const short8*)(qp + s * 16);
    } else {
      const float* qp = q + ((size_t)bh * S + q0 + l31) * D + hi * 8;
#pragma unroll
      for (int s = 0; s < 4; ++s) afrag[s] = load_frag8_f32(qp + s * 16);
    }
    f32x16 acc = {};
#pragma unroll
    for (int s = 0; s < 4; ++s)
      acc = __builtin_amdgcn_mfma_f32_32x32x16_bf16(afrag[s], bfrag[s], acc, 0, 0, 0);

    unsigned w = 0;
#pragma unroll
    for (int r = 0; r < 16; ++r) {
      int crow0 = (r & 3) + 8 * (r >> 2);
      int qrow = q0 + crow0 + 4 * hi;
      int m = mh[(size_t)qrow * S + kcol];
      if (PACK) w |= (m ? 1u : 0u) << (crow0 + 4 * hi);
      colpart += m ? __expf(acc[r] * SCALE) : 0.0f;
    }
    if (PACK) {
      w |= __shfl_xor(w, 32, 64);
      if (lane < 32) {
        int qw = it * 4 + wave;
        packed[((size_t)bh * 32 + qw) * S + kb + l31] = w;
      }
    }
  }
  colpart += __shfl_xor(colpart, 32, 64);
  __shared__ float red[4][32];
  if (lane < 32) red[wave][lane] = colpart;
  __syncthreads();
  if (tid < 32) {
    float t = red[0][tid] + red[1][tid] + red[2][tid] + red[3][tid];
    rcp[(size_t)bh * S + kb + tid] = 1.0f / t;
  }
}

// Phase 2 v2 (PRE+PACKED only): bf16 P staging in LDS, 4-tile groups with
// a wide attn-write phase (512B runs, dwordx4), double-buffered K prefetch.
__global__ __launch_bounds__(256) void attn_out2_kernel(
    const unsigned short* __restrict__ qbf, const unsigned short* __restrict__ kbf,
    const unsigned short* __restrict__ vt, const unsigned* __restrict__ packed,
    const float* __restrict__ rcp, float* __restrict__ outp,
    float* __restrict__ attnp) {
  int tid = threadIdx.x;
  int wave = tid >> 6, lane = tid & 63;
  int l31 = lane & 31, hi = lane >> 5;
  int d0 = blockIdx.x;
  int xcd = d0 & 7, idx = d0 >> 3;
  int bh = xcd * 8 + (idx >> 3);        // 8 bh per XCD (L2 locality)
  int qblk = idx & 7;
  int qb = qblk * 128 + wave * 32;
  const float* rch = rcp + (size_t)bh * S;
  float* ah = attnp + (size_t)bh * S * S;
  const unsigned short* vtb = vt + (size_t)bh * D * S;
  const unsigned short* kbb = kbf + (size_t)bh * S * D;

  // P tile staging, bf16: row stride 132 elems = 264 B (2-way banks = free,
  // 8B-aligned rows for b64 reads). 33.8 KB.
  __shared__ unsigned short pt[4][32][132];
  __shared__ unsigned wlds[4][1024];

  {
    const int4* src = (const int4*)(packed + ((size_t)bh * 32 + qblk * 4) * S);
    int4* dst = (int4*)&wlds[0][0];
#pragma unroll
    for (int j = 0; j < 4; ++j) dst[tid + j * 256] = src[tid + j * 256];
    __syncthreads();
  }

  short8 afrag[4];
  const unsigned short* qp = qbf + ((size_t)bh * S + qb + l31) * D + hi * 8;
#pragma unroll
  for (int s = 0; s < 4; ++s) afrag[s] = *(const short8*)(qp + s * 16);

  f32x16 oacc0 = {}, oacc1 = {};

  short8 bfr[2][4];
  {
    const unsigned short* kp = kbb + (size_t)l31 * D + hi * 8;
#pragma unroll
    for (int s = 0; s < 4; ++s) bfr[0][s] = *(const short8*)(kp + s * 16);
  }

  for (int g = 0; g < 8; ++g) {
#pragma unroll
    for (int tg = 0; tg < 4; ++tg) {
      int kt = g * 4 + tg;
      int kb2 = kt * 32;
      const int cur = tg & 1;   // compile-time buffer index (g*4 is even)

      // prefetch next tile's K fragments (counted vmcnt, overlaps exp loop)
      if (kt < 31) {
        const unsigned short* kp = kbb + (size_t)(kb2 + 32 + l31) * D + hi * 8;
#pragma unroll
        for (int s = 0; s < 4; ++s) bfr[cur ^ 1][s] = *(const short8*)(kp + s * 16);
      }
      // issue all 4 vT fragments early (L2-hot, land during exp loop)
      const unsigned short* vp = vtb + (size_t)l31 * S + kb2 + hi * 8;
      short8 vA0 = *(const short8*)(vp);                       // s2=0, d lo
      short8 vA1 = *(const short8*)(vp + (size_t)32 * S);      // s2=0, d hi
      short8 vB0 = *(const short8*)(vp + 16);                  // s2=1, d lo
      short8 vB1 = *(const short8*)(vp + 16 + (size_t)32 * S); // s2=1, d hi

      f32x16 acc = {};
#pragma unroll
      for (int s = 0; s < 4; ++s)
        acc = __builtin_amdgcn_mfma_f32_32x32x16_bf16(afrag[s], bfr[cur][s], acc, 0, 0, 0);

      int kcol = kb2 + l31;
      float rc = rch[kcol];
      unsigned mw = wlds[wave][kcol];
#pragma unroll
      for (int r = 0; r < 16; ++r) {
        int ql = (r & 3) + 8 * (r >> 2) + 4 * hi;
        unsigned bit = (mw >> ql) & 1u;
        float e = bit ? __expf(acc[r] * SCALE) * rc : 0.0f;
        pt[wave][ql][tg * 32 + l31] = f2bf(e);
      }

      // PV: A-fragment direct from bf16 LDS (row l31), B from registers
#pragma unroll
      for (int s2 = 0; s2 < 2; ++s2) {
        const unsigned short* pp = &pt[wave][l31][tg * 32 + s2 * 16 + hi * 8];
        s4v p0 = *(const s4v*)pp;
        s4v p1 = *(const s4v*)(pp + 4);
        short8 pa;
        pa[0] = p0[0]; pa[1] = p0[1]; pa[2] = p0[2]; pa[3] = p0[3];
        pa[4] = p1[0]; pa[5] = p1[1]; pa[6] = p1[2]; pa[7] = p1[3];
        oacc0 = __builtin_amdgcn_mfma_f32_32x32x16_bf16(pa, s2 ? vB0 : vA0, oacc0, 0, 0, 0);
        oacc1 = __builtin_amdgcn_mfma_f32_32x32x16_bf16(pa, s2 ? vB1 : vA1, oacc1, 0, 0, 0);
      }
    }

    // attn write phase for group g: 32 rows x 512 B contiguous runs.
#pragma unroll
    for (int it = 0; it < 8; ++it) {
      int row = it * 4 + (lane >> 4);
      int seg = lane & 15;
      const unsigned short* pp = &pt[wave][row][seg * 8];
      s4v a = *(const s4v*)pp;
      s4v b = *(const s4v*)(pp + 4);
      float4 f0, f1;
      f0.x = bf2f((unsigned short)a[0]); f0.y = bf2f((unsigned short)a[1]);
      f0.z = bf2f((unsigned short)a[2]); f0.w = bf2f((unsigned short)a[3]);
      f1.x = bf2f((unsigned short)b[0]); f1.y = bf2f((unsigned short)b[1]);
      f1.z = bf2f((unsigned short)b[2]); f1.w = bf2f((unsigned short)b[3]);
      float* dst = &ah[(size_t)(qb + row) * S + g * 128 + seg * 8];
      *(float4*)dst = f0;
      *(float4*)(dst + 4) = f1;
    }
  }

  float* oh = outp + (size_t)bh * S * D;
#pragma unroll
  for (int r = 0; r < 16; ++r) {
    int ql = (r & 3) + 8 * (r >> 2) + 4 * hi;
    oh[(size_t)(qb + ql) * D + l31] = oacc0[r];
    oh[(size_t)(qb + ql) * D + 32 + l31] = oacc1[r];
  }
}

// Fallback phase 2 (round-6 structure) for small-workspace paths.
template <bool PACKED>
__global__ __launch_bounds__(256) void attn_out_kernel(
    const float* __restrict__ q, const float* __restrict__ k,
    const float* __restrict__ v, const int* __restrict__ mask,
    const unsigned* __restrict__ packed, const float* __restrict__ rcp,
    float* __restrict__ outp, float* __restrict__ attnp) {
  int tid = threadIdx.x;
  int wave = tid >> 6, lane = tid & 63;
  int l31 = lane & 31, hi = lane >> 5;
  int bh = blockIdx.y;
  int qb = blockIdx.x * 128 + wave * 32;
  const int* mh = mask + (size_t)bh * S * S;
  const float* rch = rcp + (size_t)bh * S;
  float* ah = attnp + (size_t)bh * S * S;

  __shared__ float sm[4][32][33];
  __shared__ unsigned wlds[4][1024];

  if (PACKED) {
    const int4* src = (const int4*)(packed + ((size_t)bh * 32 + blockIdx.x * 4) * S);
    int4* dst = (int4*)&wlds[0][0];
#pragma unroll
    for (int j = 0; j < 4; ++j) dst[tid + j * 256] = src[tid + j * 256];
    __syncthreads();
  }

  short8 afrag[4];
  const float* qp = q + ((size_t)bh * S + qb + l31) * D + hi * 8;
#pragma unroll
  for (int s = 0; s < 4; ++s) afrag[s] = load_frag8_f32(qp + s * 16);

  f32x16 oacc0 = {}, oacc1 = {};

  for (int kt = 0; kt < 32; ++kt) {
    int kb2 = kt * 32;
    const float* kp = k + ((size_t)bh * S + kb2 + l31) * D + hi * 8;
    short8 bfrag[4];
#pragma unroll
    for (int s = 0; s < 4; ++s) bfrag[s] = load_frag8_f32(kp + s * 16);
    f32x16 acc = {};
#pragma unroll
    for (int s = 0; s < 4; ++s)
      acc = __builtin_amdgcn_mfma_f32_32x32x16_bf16(afrag[s], bfrag[s], acc, 0, 0, 0);

    int kcol = kb2 + l31;
    float rc = rch[kcol];
    unsigned mw = PACKED ? wlds[wave][kcol] : 0u;
#pragma unroll
    for (int r = 0; r < 16; ++r) {
      int ql = (r & 3) + 8 * (r >> 2) + 4 * hi;
      int qrow = qb + ql;
      unsigned bit;
      if (PACKED) bit = (mw >> ql) & 1u;
      else        bit = mh[(size_t)qrow * S + kcol] ? 1u : 0u;
      float e = bit ? __expf(acc[r] * SCALE) * rc : 0.0f;
      ah[(size_t)qrow * S + kcol] = e;
      sm[wave][ql][l31] = e;
    }
#pragma unroll
    for (int s2 = 0; s2 < 2; ++s2) {
      short8 pa;
      const float* smrow = &sm[wave][l31][0];
#pragma unroll
      for (int e = 0; e < 8; ++e) pa[e] = (short)f2bf(smrow[s2 * 16 + hi * 8 + e]);
      const float* vp = v + ((size_t)bh * S + kb2 + s2 * 16 + hi * 8) * D + l31;
      short8 vf0, vf1;
#pragma unroll
      for (int e = 0; e < 8; ++e) {
        vf0[e] = (short)f2bf(vp[(size_t)e * D]);
        vf1[e] = (short)f2bf(vp[(size_t)e * D + 32]);
      }
      oacc0 = __builtin_amdgcn_mfma_f32_32x32x16_bf16(pa, vf0, oacc0, 0, 0, 0);
      oacc1 = __builtin_amdgcn_mfma_f32_32x32x16_bf16(pa, vf1, oacc1, 0, 0, 0);
    }
  }

  float* oh = outp + (size_t)bh * S * D;
#pragma unroll
  for (int r = 0; r < 16; ++r) {
    int ql = (r & 3) + 8 * (r >> 2) + 4 * hi;
    oh[(size_t)(qb + ql) * D + l31] = oacc0[r];
    oh[(size_t)(qb + ql) * D + 32 + l31] = oacc1[r];
  }
}

extern "C" void kernel_launch(void* const* d_in, const int* in_sizes, int n_in,
                              void* d_out, int out_size, void* d_ws, size_t ws_size,
                              hipStream_t stream) {
  const float* q = (const float*)d_in[0];
  const float* k = (const float*)d_in[1];
  const float* v = (const float*)d_in[2];
  const int* mask = (const int*)d_in[3];
  float* outp = (float*)d_out;
  float* attnp = outp + (size_t)BH * S * D;  // out first, then attn
  float* rcp = (float*)d_ws;                 // 256 KB
  size_t rcp_bytes = (size_t)BH * S * 4;
  size_t packed_bytes = (size_t)BH * 32 * S * 4;  // 8.4 MB
  size_t bf_bytes = (size_t)BH * S * D * 2;       // 8.4 MB each

  unsigned* packed = (unsigned*)((char*)d_ws + rcp_bytes);
  unsigned short* qbf = (unsigned short*)((char*)d_ws + rcp_bytes + packed_bytes);
  unsigned short* kbf = qbf + (size_t)BH * S * D;
  unsigned short* vt = kbf + (size_t)BH * S * D;

  if (ws_size >= rcp_bytes + packed_bytes + 3 * bf_bytes) {
    cvt_kernel<<<dim3(1024, 2), 256, 0, stream>>>(q, k, qbf, kbf);
    vt_kernel<<<dim3(16, BH), 256, 0, stream>>>(v, vt);
    colsum_kernel<true, true><<<2048, 256, 0, stream>>>(
        q, k, qbf, kbf, mask, rcp, packed);
    attn_out2_kernel<<<512, 256, 0, stream>>>(qbf, kbf, vt, packed, rcp, outp, attnp);
  } else if (ws_size >= rcp_bytes + packed_bytes) {
    colsum_kernel<false, true><<<2048, 256, 0, stream>>>(
        q, k, nullptr, nullptr, mask, rcp, packed);
    attn_out_kernel<true><<<dim3(S / 128, BH), 256, 0, stream>>>(
        q, k, v, mask, packed, rcp, outp, attnp);
  } else {
    colsum_kernel<false, false><<<2048, 256, 0, stream>>>(
        q, k, nullptr, nullptr, mask, rcp, nullptr);
    attn_out_kernel<false><<<dim3(S / 128, BH), 256, 0, stream>>>(
        q, k, v, mask, nullptr, rcp, outp, attnp);
  }
}

// Round 10
// 206.743 us; speedup vs baseline: 2.4169x; 1.1690x over previous
//
#include <hip/hip_runtime.h>
#include <hip/hip_bf16.h>

#define S 1024
#define D 64
#define BH 64
#define SCALE 0.125f

typedef __attribute__((ext_vector_type(8))) short short8;
typedef __attribute__((ext_vector_type(4))) short s4v;
typedef __attribute__((ext_vector_type(16))) float f32x16;

// fp32 -> bf16 RNE. Plain bit ops, NO inline asm (rounds 2-4 regression).
static __device__ __forceinline__ unsigned short f2bf(float f) {
  union { float f; unsigned u; } v; v.f = f;
  return (unsigned short)((v.u + 0x7fffu + ((v.u >> 16) & 1u)) >> 16);
}

static __device__ __forceinline__ float bf2f(unsigned short h) {
  union { unsigned u; float f; } v; v.u = (unsigned)h << 16; return v.f;
}

static __device__ __forceinline__ short8 load_frag8_f32(const float* p) {
  float4 a = *(const float4*)p;
  float4 b = *(const float4*)(p + 4);
  short8 r;
  r[0] = f2bf(a.x); r[1] = f2bf(a.y); r[2] = f2bf(a.z); r[3] = f2bf(a.w);
  r[4] = f2bf(b.x); r[5] = f2bf(b.y); r[6] = f2bf(b.z); r[7] = f2bf(b.w);
  return r;
}

// Pre-pass A: q,k fp32 -> bf16 straight convert.
__global__ __launch_bounds__(256) void cvt_kernel(
    const float* __restrict__ s0, const float* __restrict__ s1,
    unsigned short* __restrict__ d0, unsigned short* __restrict__ d1) {
  const float* s = blockIdx.y == 0 ? s0 : s1;
  unsigned short* d = blockIdx.y == 0 ? d0 : d1;
  size_t i = (size_t)(blockIdx.x * 256 + threadIdx.x) * 8;
#pragma unroll
  for (int c = 0; c < 2; ++c, i += (size_t)1024 * 256 * 8)
    *(short8*)(d + i) = load_frag8_f32(s + i);
}

// Pre-pass B: v fp32 [bh][s][d] -> vT bf16 [bh][d][s] via 64x64 LDS tile.
__global__ __launch_bounds__(256) void vt_kernel(
    const float* __restrict__ v, unsigned short* __restrict__ vt) {
  __shared__ float t[64][65];
  int bh = blockIdx.y;
  int s0 = blockIdx.x * 64;
  int tid = threadIdx.x;
  {
    int r = tid >> 2, c4 = (tid & 3) * 16;
    const float4* src = (const float4*)(v + ((size_t)bh * S + s0 + r) * D + c4);
#pragma unroll
    for (int j = 0; j < 4; ++j) {
      float4 x = src[j];
      t[r][c4 + j * 4 + 0] = x.x; t[r][c4 + j * 4 + 1] = x.y;
      t[r][c4 + j * 4 + 2] = x.z; t[r][c4 + j * 4 + 3] = x.w;
    }
  }
  __syncthreads();
  {
    int d = tid >> 2, sc = (tid & 3) * 16;
    unsigned short* dst = vt + ((size_t)bh * D + d) * S + s0 + sc;
    short8 o0, o1;
#pragma unroll
    for (int j = 0; j < 8; ++j) {
      o0[j] = (short)f2bf(t[sc + j][d]);
      o1[j] = (short)f2bf(t[sc + 8 + j][d]);
    }
    *(short8*)dst = o0;
    *(short8*)(dst + 8) = o1;
  }
}

// Phase 1: rcp + packed mask, XCD-swizzled. Round-8 structure; only change:
// NON-TEMPORAL mask loads so the 268MB read-once stream doesn't evict the
// L2-resident qbf/kbf slices that the 32 sibling blocks per bh re-read.
template <bool PRE, bool PACK>
__global__ __launch_bounds__(256) void colsum_kernel(
    const float* __restrict__ q, const float* __restrict__ k,
    const unsigned short* __restrict__ qbf, const unsigned short* __restrict__ kbf,
    const int* __restrict__ mask, float* __restrict__ rcp,
    unsigned* __restrict__ packed) {
  int tid = threadIdx.x;
  int wave = tid >> 6, lane = tid & 63;
  int l31 = lane & 31, hi = lane >> 5;
  int d0 = blockIdx.x;
  int xcd = d0 & 7, idx = d0 >> 3;
  int bh = xcd * 8 + (idx >> 5);
  int kbi = idx & 31;
  int kb = kbi * 32;
  const int* mh = mask + (size_t)bh * S * S;

  short8 bfrag[4];
  if (PRE) {
    const unsigned short* kp = kbf + ((size_t)bh * S + kb + l31) * D + hi * 8;
#pragma unroll
    for (int s = 0; s < 4; ++s) bfrag[s] = *(const short8*)(kp + s * 16);
  } else {
    const float* kp = k + ((size_t)bh * S + kb + l31) * D + hi * 8;
#pragma unroll
    for (int s = 0; s < 4; ++s) bfrag[s] = load_frag8_f32(kp + s * 16);
  }

  int kcol = kb + l31;
  float colpart = 0.f;
  for (int it = 0; it < 8; ++it) {
    int q0 = it * 128 + wave * 32;
    short8 afrag[4];
    if (PRE) {
      const unsigned short* qp = qbf + ((size_t)bh * S + q0 + l31) * D + hi * 8;
#pragma unroll
      for (int s = 0; s < 4; ++s) afrag[s] = *(const short8*)(qp + s * 16);
    } else {
      const float* qp = q + ((size_t)bh * S + q0 + l31) * D + hi * 8;
#pragma unroll
      for (int s = 0; s < 4; ++s) afrag[s] = load_frag8_f32(qp + s * 16);
    }
    f32x16 acc = {};
#pragma unroll
    for (int s = 0; s < 4; ++s)
      acc = __builtin_amdgcn_mfma_f32_32x32x16_bf16(afrag[s], bfrag[s], acc, 0, 0, 0);

    unsigned w = 0;
#pragma unroll
    for (int r = 0; r < 16; ++r) {
      int crow0 = (r & 3) + 8 * (r >> 2);
      int qrow = q0 + crow0 + 4 * hi;
      int m = __builtin_nontemporal_load(mh + (size_t)qrow * S + kcol);
      if (PACK) w |= (m ? 1u : 0u) << (crow0 + 4 * hi);
      colpart += m ? __expf(acc[r] * SCALE) : 0.0f;
    }
    if (PACK) {
      w |= __shfl_xor(w, 32, 64);
      if (lane < 32) {
        int qw = it * 4 + wave;
        packed[((size_t)bh * 32 + qw) * S + kb + l31] = w;
      }
    }
  }
  colpart += __shfl_xor(colpart, 32, 64);
  __shared__ float red[4][32];
  if (lane < 32) red[wave][lane] = colpart;
  __syncthreads();
  if (tid < 32) {
    float t = red[0][tid] + red[1][tid] + red[2][tid] + red[3][tid];
    rcp[(size_t)bh * S + kb + tid] = 1.0f / t;
  }
}

// Phase 2 v3: block-level LDS staging of k-tile (32x64 bf16, 144B padded
// rows) and vT-tile (64x32 bf16, 80B padded rows), double-buffered,
// cooperative coalesced loads (256 thr x 16B = 4KB bursts). 4x less L2-side
// operand traffic vs per-wave frag loads; pad rows give only 4-way LDS
// conflicts (~free). bf16 P staging + grouped 512B attn writes kept.
__global__ __launch_bounds__(256) void attn_out3_kernel(
    const unsigned short* __restrict__ qbf, const unsigned short* __restrict__ kbf,
    const unsigned short* __restrict__ vt, const unsigned* __restrict__ packed,
    const float* __restrict__ rcp, float* __restrict__ outp,
    float* __restrict__ attnp) {
  int tid = threadIdx.x;
  int wave = tid >> 6, lane = tid & 63;
  int l31 = lane & 31, hi = lane >> 5;
  int d0 = blockIdx.x;
  int xcd = d0 & 7, idx = d0 >> 3;
  int bh = xcd * 8 + (idx >> 3);        // 8 bh per XCD (L2 locality)
  int qblk = idx & 7;
  int qb = qblk * 128 + wave * 32;
  const float* rch = rcp + (size_t)bh * S;
  float* ah = attnp + (size_t)bh * S * S;
  const unsigned short* vtb = vt + (size_t)bh * D * S;
  const unsigned short* kbb = kbf + (size_t)bh * S * D;

  __shared__ unsigned short kst[2][32][72];  // 144B rows -> 4-way reads
  __shared__ unsigned short vst[2][64][40];  // 80B rows  -> 4-way reads
  __shared__ unsigned short pt[4][32][132];  // per-wave P tile (264B rows)
  __shared__ unsigned wlds[4][1024];

  int tr3 = tid >> 3, tc8 = tid & 7;  // k-tile stage: row, 16B chunk
  int vr2 = tid >> 2, vc4 = tid & 3;  // v-tile stage: row(d), 16B chunk

  // stage tile 0 + packed mask
  short8 kreg = *(const short8*)(kbb + (size_t)tr3 * D + tc8 * 8);
  short8 vreg = *(const short8*)(vtb + (size_t)vr2 * S + vc4 * 8);
  {
    const int4* src = (const int4*)(packed + ((size_t)bh * 32 + qblk * 4) * S);
    int4* dst = (int4*)&wlds[0][0];
#pragma unroll
    for (int j = 0; j < 4; ++j) dst[tid + j * 256] = src[tid + j * 256];
  }
  short8 afrag[4];
  {
    const unsigned short* qp = qbf + ((size_t)bh * S + qb + l31) * D + hi * 8;
#pragma unroll
    for (int s = 0; s < 4; ++s) afrag[s] = *(const short8*)(qp + s * 16);
  }
  *(short8*)&kst[0][tr3][tc8 * 8] = kreg;
  *(short8*)&vst[0][vr2][vc4 * 8] = vreg;
  __syncthreads();

  f32x16 oacc0 = {}, oacc1 = {};

  for (int g = 0; g < 8; ++g) {
#pragma unroll
    for (int tg = 0; tg < 4; ++tg) {
      int kt = g * 4 + tg;
      int kb2 = kt * 32;
      const int cur = tg & 1;  // == kt&1 (g*4 even): compile-time index

      // prefetch next tile into regs (lands during compute, T14 pattern)
      if (kt < 31) {
        kreg = *(const short8*)(kbb + (size_t)(kb2 + 32 + tr3) * D + tc8 * 8);
        vreg = *(const short8*)(vtb + (size_t)vr2 * S + kb2 + 32 + vc4 * 8);
      }

      // QK^T from LDS k-tile
      short8 bfrag[4];
#pragma unroll
      for (int s = 0; s < 4; ++s)
        bfrag[s] = *(const short8*)&kst[cur][l31][hi * 8 + s * 16];
      f32x16 acc = {};
#pragma unroll
      for (int s = 0; s < 4; ++s)
        acc = __builtin_amdgcn_mfma_f32_32x32x16_bf16(afrag[s], bfrag[s], acc, 0, 0, 0);

      // V fragments from LDS vT-tile
      short8 vA0 = *(const short8*)&vst[cur][l31][hi * 8];
      short8 vA1 = *(const short8*)&vst[cur][l31 + 32][hi * 8];
      short8 vB0 = *(const short8*)&vst[cur][l31][16 + hi * 8];
      short8 vB1 = *(const short8*)&vst[cur][l31 + 32][16 + hi * 8];

      int kcol = kb2 + l31;
      float rc = rch[kcol];
      unsigned mw = wlds[wave][kcol];
#pragma unroll
      for (int r = 0; r < 16; ++r) {
        int ql = (r & 3) + 8 * (r >> 2) + 4 * hi;
        unsigned bit = (mw >> ql) & 1u;
        float e = bit ? __expf(acc[r] * SCALE) * rc : 0.0f;
        pt[wave][ql][tg * 32 + l31] = f2bf(e);
      }

      // PV: A from bf16 LDS P row, B from vT LDS fragments
#pragma unroll
      for (int s2 = 0; s2 < 2; ++s2) {
        const unsigned short* pp = &pt[wave][l31][tg * 32 + s2 * 16 + hi * 8];
        s4v p0 = *(const s4v*)pp;
        s4v p1 = *(const s4v*)(pp + 4);
        short8 pa;
        pa[0] = p0[0]; pa[1] = p0[1]; pa[2] = p0[2]; pa[3] = p0[3];
        pa[4] = p1[0]; pa[5] = p1[1]; pa[6] = p1[2]; pa[7] = p1[3];
        oacc0 = __builtin_amdgcn_mfma_f32_32x32x16_bf16(pa, s2 ? vB0 : vA0, oacc0, 0, 0, 0);
        oacc1 = __builtin_amdgcn_mfma_f32_32x32x16_bf16(pa, s2 ? vB1 : vA1, oacc1, 0, 0, 0);
      }

      // write prefetched tile to the other buffer, then sync
      if (kt < 31) {
        *(short8*)&kst[cur ^ 1][tr3][tc8 * 8] = kreg;
        *(short8*)&vst[cur ^ 1][vr2][vc4 * 8] = vreg;
      }
      __syncthreads();
    }

    // attn write phase for group g: 32 rows x 512B contiguous runs.
#pragma unroll
    for (int it = 0; it < 8; ++it) {
      int row = it * 4 + (lane >> 4);
      int seg = lane & 15;
      const unsigned short* pp = &pt[wave][row][seg * 8];
      s4v a = *(const s4v*)pp;
      s4v b = *(const s4v*)(pp + 4);
      float4 f0, f1;
      f0.x = bf2f((unsigned short)a[0]); f0.y = bf2f((unsigned short)a[1]);
      f0.z = bf2f((unsigned short)a[2]); f0.w = bf2f((unsigned short)a[3]);
      f1.x = bf2f((unsigned short)b[0]); f1.y = bf2f((unsigned short)b[1]);
      f1.z = bf2f((unsigned short)b[2]); f1.w = bf2f((unsigned short)b[3]);
      float* dst = &ah[(size_t)(qb + row) * S + g * 128 + seg * 8];
      *(float4*)dst = f0;
      *(float4*)(dst + 4) = f1;
    }
  }

  float* oh = outp + (size_t)bh * S * D;
#pragma unroll
  for (int r = 0; r < 16; ++r) {
    int ql = (r & 3) + 8 * (r >> 2) + 4 * hi;
    oh[(size_t)(qb + ql) * D + l31] = oacc0[r];
    oh[(size_t)(qb + ql) * D + 32 + l31] = oacc1[r];
  }
}

// Fallback phase 2 (round-6 structure) for small-workspace paths.
template <bool PACKED>
__global__ __launch_bounds__(256) void attn_out_kernel(
    const float* __restrict__ q, const float* __restrict__ k,
    const float* __restrict__ v, const int* __restrict__ mask,
    const unsigned* __restrict__ packed, const float* __restrict__ rcp,
    float* __restrict__ outp, float* __restrict__ attnp) {
  int tid = threadIdx.x;
  int wave = tid >> 6, lane = tid & 63;
  int l31 = lane & 31, hi = lane >> 5;
  int bh = blockIdx.y;
  int qb = blockIdx.x * 128 + wave * 32;
  const int* mh = mask + (size_t)bh * S * S;
  const float* rch = rcp + (size_t)bh * S;
  float* ah = attnp + (size_t)bh * S * S;

  __shared__ float sm[4][32][33];
  __shared__ unsigned wlds[4][1024];

  if (PACKED) {
    const int4* src = (const int4*)(packed + ((size_t)bh * 32 + blockIdx.x * 4) * S);
    int4* dst = (int4*)&wlds[0][0];
#pragma unroll
    for (int j = 0; j < 4; ++j) dst[tid + j * 256] = src[tid + j * 256];
    __syncthreads();
  }

  short8 afrag[4];
  const float* qp = q + ((size_t)bh * S + qb + l31) * D + hi * 8;
#pragma unroll
  for (int s = 0; s < 4; ++s) afrag[s] = load_frag8_f32(qp + s * 16);

  f32x16 oacc0 = {}, oacc1 = {};

  for (int kt = 0; kt < 32; ++kt) {
    int kb2 = kt * 32;
    const float* kp = k + ((size_t)bh * S + kb2 + l31) * D + hi * 8;
    short8 bfrag[4];
#pragma unroll
    for (int s = 0; s < 4; ++s) bfrag[s] = load_frag8_f32(kp + s * 16);
    f32x16 acc = {};
#pragma unroll
    for (int s = 0; s < 4; ++s)
      acc = __builtin_amdgcn_mfma_f32_32x32x16_bf16(afrag[s], bfrag[s], acc, 0, 0, 0);

    int kcol = kb2 + l31;
    float rc = rch[kcol];
    unsigned mw = PACKED ? wlds[wave][kcol] : 0u;
#pragma unroll
    for (int r = 0; r < 16; ++r) {
      int ql = (r & 3) + 8 * (r >> 2) + 4 * hi;
      int qrow = qb + ql;
      unsigned bit;
      if (PACKED) bit = (mw >> ql) & 1u;
      else        bit = mh[(size_t)qrow * S + kcol] ? 1u : 0u;
      float e = bit ? __expf(acc[r] * SCALE) * rc : 0.0f;
      ah[(size_t)qrow * S + kcol] = e;
      sm[wave][ql][l31] = e;
    }
#pragma unroll
    for (int s2 = 0; s2 < 2; ++s2) {
      short8 pa;
      const float* smrow = &sm[wave][l31][0];
#pragma unroll
      for (int e = 0; e < 8; ++e) pa[e] = (short)f2bf(smrow[s2 * 16 + hi * 8 + e]);
      const float* vp = v + ((size_t)bh * S + kb2 + s2 * 16 + hi * 8) * D + l31;
      short8 vf0, vf1;
#pragma unroll
      for (int e = 0; e < 8; ++e) {
        vf0[e] = (short)f2bf(vp[(size_t)e * D]);
        vf1[e] = (short)f2bf(vp[(size_t)e * D + 32]);
      }
      oacc0 = __builtin_amdgcn_mfma_f32_32x32x16_bf16(pa, vf0, oacc0, 0, 0, 0);
      oacc1 = __builtin_amdgcn_mfma_f32_32x32x16_bf16(pa, vf1, oacc1, 0, 0, 0);
    }
  }

  float* oh = outp + (size_t)bh * S * D;
#pragma unroll
  for (int r = 0; r < 16; ++r) {
    int ql = (r & 3) + 8 * (r >> 2) + 4 * hi;
    oh[(size_t)(qb + ql) * D + l31] = oacc0[r];
    oh[(size_t)(qb + ql) * D + 32 + l31] = oacc1[r];
  }
}

extern "C" void kernel_launch(void* const* d_in, const int* in_sizes, int n_in,
                              void* d_out, int out_size, void* d_ws, size_t ws_size,
                              hipStream_t stream) {
  const float* q = (const float*)d_in[0];
  const float* k = (const float*)d_in[1];
  const float* v = (const float*)d_in[2];
  const int* mask = (const int*)d_in[3];
  float* outp = (float*)d_out;
  float* attnp = outp + (size_t)BH * S * D;  // out first, then attn
  float* rcp = (float*)d_ws;                 // 256 KB
  size_t rcp_bytes = (size_t)BH * S * 4;
  size_t packed_bytes = (size_t)BH * 32 * S * 4;  // 8.4 MB
  size_t bf_bytes = (size_t)BH * S * D * 2;       // 8.4 MB each

  unsigned* packed = (unsigned*)((char*)d_ws + rcp_bytes);
  unsigned short* qbf = (unsigned short*)((char*)d_ws + rcp_bytes + packed_bytes);
  unsigned short* kbf = qbf + (size_t)BH * S * D;
  unsigned short* vt = kbf + (size_t)BH * S * D;

  if (ws_size >= rcp_bytes + packed_bytes + 3 * bf_bytes) {
    cvt_kernel<<<dim3(1024, 2), 256, 0, stream>>>(q, k, qbf, kbf);
    vt_kernel<<<dim3(16, BH), 256, 0, stream>>>(v, vt);
    colsum_kernel<true, true><<<2048, 256, 0, stream>>>(
        q, k, qbf, kbf, mask, rcp, packed);
    attn_out3_kernel<<<512, 256, 0, stream>>>(qbf, kbf, vt, packed, rcp, outp, attnp);
  } else if (ws_size >= rcp_bytes + packed_bytes) {
    colsum_kernel<false, true><<<2048, 256, 0, stream>>>(
        q, k, nullptr, nullptr, mask, rcp, packed);
    attn_out_kernel<true><<<dim3(S / 128, BH), 256, 0, stream>>>(
        q, k, v, mask, packed, rcp, outp, attnp);
  } else {
    colsum_kernel<false, false><<<2048, 256, 0, stream>>>(
        q, k, nullptr, nullptr, mask, rcp, nullptr);
    attn_out_kernel<false><<<dim3(S / 128, BH), 256, 0, stream>>>(
        q, k, v, mask, nullptr, rcp, outp, attnp);
  }
}